// Round 6
// baseline (323.177 us; speedup 1.0000x reference)
//
#include <hip/hip_runtime.h>
#include <hip/hip_cooperative_groups.h>
#include <math.h>

namespace cg = cooperative_groups;

#define NB 16
#define NN 2048
#define NF 128
#define NH 128
#define NO 64

typedef short bf16x8 __attribute__((ext_vector_type(8)));
typedef float f32x4 __attribute__((ext_vector_type(4)));
typedef unsigned short u16;
typedef unsigned int u32;

__device__ __forceinline__ u16 f2bf(float f) {
  u32 u = __builtin_bit_cast(u32, f);
  return (u16)((u + 0x7fffu + ((u >> 16) & 1u)) >> 16);
}
__device__ __forceinline__ float bf2f(u16 h) {
  u32 u = ((u32)h) << 16;
  return __builtin_bit_cast(float, u);
}
__device__ __forceinline__ float lrelu(float x) { return x > 0.f ? x : 0.2f * x; }

__device__ __forceinline__ void gload16(const void* g, void* l) {
  __builtin_amdgcn_global_load_lds((const __attribute__((address_space(1))) void*)g,
                                   (__attribute__((address_space(3))) void*)l, 16, 0, 0);
}
__device__ __forceinline__ f32x4 mfma16(bf16x8 a, bf16x8 b, f32x4 c) {
  return __builtin_amdgcn_mfma_f32_16x16x32_bf16(a, b, c, 0, 0, 0);
}

// ---------------- K_prep: all input preprocessing in one kernel --------------
// bid 0      : gWT[c][k] = gat_w[k][c] (fp32)
// bid 1..8   : Wsw  = gcn_w bf16 in [kblk 16][d 128][8] image
// bid 9..264 : x_sw = x bf16 in [rowblk 256][kblk 16][row 128][8] image
// bid 265..  : adj_sw = adj bf16 in [ntile 32][ktile 32][kblk 8][row 64][8] image
__global__ __launch_bounds__(256) void k_prep(const float* __restrict__ x,
                                              const float* __restrict__ adj,
                                              const float* __restrict__ gcn_w,
                                              const float* __restrict__ gat_w,
                                              u16* __restrict__ x_sw,
                                              u16* __restrict__ adj_sw,
                                              float* __restrict__ gWT,
                                              u16* __restrict__ Wsw) {
  __shared__ u16 ts[128 * 136];
  const int t = threadIdx.x;
  const int bid = blockIdx.x;
  if (bid == 0) {
    const int c = t & 63, kq = t >> 6;
    for (int k = kq * 32; k < kq * 32 + 32; ++k) gWT[c * 128 + k] = gat_w[k * 64 + c];
  } else if (bid < 9) {
    const int s = (bid - 1) * 256 + t;  // [kb 16][d 128]
    const int kb = s >> 7, d = s & 127;
    u16 tmp[8];
#pragma unroll
    for (int j = 0; j < 8; ++j) tmp[j] = f2bf(gcn_w[(kb * 8 + j) * 128 + d]);
    uint4 o;
    o.x = (u32)tmp[0] | ((u32)tmp[1] << 16);
    o.y = (u32)tmp[2] | ((u32)tmp[3] << 16);
    o.z = (u32)tmp[4] | ((u32)tmp[5] << 16);
    o.w = (u32)tmp[6] | ((u32)tmp[7] << 16);
    *(uint4*)&Wsw[(size_t)s * 8] = o;
  } else if (bid < 265) {
    const int blk = bid - 9;  // 128 rows of x
    const size_t r0 = (size_t)blk * 128;
#pragma unroll
    for (int k = 0; k < 16; ++k) {
      const int s = t + k * 256;  // 4096 float4 slots
      const int row = s >> 5, c4 = (s & 31) * 4;
      const float4 f = *(const float4*)&x[(r0 + row) * 128 + c4];
      uint2 pk;
      pk.x = (u32)f2bf(f.x) | ((u32)f2bf(f.y) << 16);
      pk.y = (u32)f2bf(f.z) | ((u32)f2bf(f.w) << 16);
      *(uint2*)&ts[row * 136 + c4] = pk;
    }
    __syncthreads();
#pragma unroll
    for (int k = 0; k < 8; ++k) {
      const int s = t + k * 256;  // 2048 16B slots: [kb 16][row 128]
      const int kb = s >> 7, row = s & 127;
      const uint4 v = *(const uint4*)&ts[row * 136 + kb * 8];
      *(uint4*)&x_sw[(size_t)blk * 16384 + (size_t)s * 8] = v;
    }
  } else {
    const int tile = bid - 265;  // 64x64 tile of adj: [nt 32][kt 32]
    const int n0 = (tile >> 5) * 64, m0 = (tile & 31) * 64;
#pragma unroll
    for (int k = 0; k < 4; ++k) {
      const int s = t + k * 256;  // 1024 float4 slots
      const int row = s >> 4, c4 = (s & 15) * 4;
      const float4 f = *(const float4*)&adj[(size_t)(n0 + row) * 2048 + m0 + c4];
      uint2 pk;
      pk.x = (u32)f2bf(f.x) | ((u32)f2bf(f.y) << 16);
      pk.y = (u32)f2bf(f.z) | ((u32)f2bf(f.w) << 16);
      *(uint2*)&ts[row * 136 + c4] = pk;
    }
    __syncthreads();
#pragma unroll
    for (int k = 0; k < 2; ++k) {
      const int s = t + k * 256;  // 512 16B slots: [kb 8][row 64]
      const int kb = s >> 6, row = s & 63;
      const uint4 v = *(const uint4*)&ts[row * 136 + kb * 8];
      *(uint4*)&adj_sw[(size_t)tile * 4096 + (size_t)s * 8] = v;
    }
  }
}

// ---------------- K_support: suppT_sw = (x @ W)^T, pre-swizzled bf16 ---------
__global__ __launch_bounds__(256) void k_support(const u16* __restrict__ x_sw,
                                                 const u16* __restrict__ Wsw,
                                                 u16* __restrict__ suppT_sw) {
  const int m0g = blockIdx.x * 128;
  const int t = threadIdx.x, w = t >> 6, l = t & 63;
  const int lg = l >> 4, lr = l & 15;
  __shared__ __align__(16) u16 sh[32768];  // 64KB stage; reused as os
  u16* As = sh;
  u16* Bs = sh + 16384;
#pragma unroll
  for (int i = 0; i < 8; ++i) {
    const int s0 = i * 256 + w * 64;
    gload16(x_sw + (size_t)blockIdx.x * 16384 + (size_t)(s0 + l) * 8, &As[(size_t)s0 * 8]);
  }
#pragma unroll
  for (int i = 0; i < 8; ++i) {
    const int s0 = i * 256 + w * 64;
    gload16(Wsw + (size_t)(s0 + l) * 8, &Bs[(size_t)s0 * 8]);
  }
  __syncthreads();
  f32x4 acc[2][8];
#pragma unroll
  for (int mf = 0; mf < 2; ++mf)
#pragma unroll
    for (int nf = 0; nf < 8; ++nf) {
      acc[mf][nf][0] = 0.f; acc[mf][nf][1] = 0.f;
      acc[mf][nf][2] = 0.f; acc[mf][nf][3] = 0.f;
    }
#pragma unroll
  for (int ks = 0; ks < 4; ++ks) {
    const int kb = ks * 4 + lg;
    const bf16x8 a0 = *(const bf16x8*)&As[((size_t)kb * 128 + w * 32 + lr) * 8];
    const bf16x8 a1 = *(const bf16x8*)&As[((size_t)kb * 128 + w * 32 + 16 + lr) * 8];
#pragma unroll
    for (int nf = 0; nf < 8; ++nf) {
      const bf16x8 b = *(const bf16x8*)&Bs[((size_t)kb * 128 + nf * 16 + lr) * 8];
      acc[0][nf] = mfma16(a0, b, acc[0][nf]);
      acc[1][nf] = mfma16(a1, b, acc[1][nf]);
    }
  }
  __syncthreads();
  u16* os = sh;  // transpose: os[d][m_local], stride 136 u16
#pragma unroll
  for (int nf = 0; nf < 8; ++nf) {
    const int d = nf * 16 + lr;
#pragma unroll
    for (int mf = 0; mf < 2; ++mf) {
      const int mb = w * 32 + mf * 16 + lg * 4;
      const u32 p0 = (u32)f2bf(acc[mf][nf][0]) | ((u32)f2bf(acc[mf][nf][1]) << 16);
      const u32 p1 = (u32)f2bf(acc[mf][nf][2]) | ((u32)f2bf(acc[mf][nf][3]) << 16);
      *(u32*)&os[d * 136 + mb] = p0;
      *(u32*)&os[d * 136 + mb + 2] = p1;
    }
  }
  __syncthreads();
  const int b = m0g >> 11, mt0 = (m0g & 2047) >> 6;
#pragma unroll
  for (int i = 0; i < 8; ++i) {
    const int s = i * 256 + t;  // [kt 2][kb 8][d 128]
    const int kt = s >> 10, kb = (s >> 7) & 7, d = s & 127;
    const uint4 v = *(const uint4*)&os[d * 136 + kt * 64 + kb * 8];
    *(uint4*)&suppT_sw[((size_t)((b * 32 + mt0 + kt) * 8 + kb)) * 1024 + (size_t)d * 8] = v;
  }
}

// ---------------- K_fused (cooperative): gcn -> BN -> hp -> attnA -> attnB ---
// grid (32 nt, 16 b), 256 threads, 2 blocks/CU co-resident (512 total).
// LDS union SB (51200 B):
//   P1 : As u16[2][4096] @0 | Bs u16[2][8192] @8192 | red f32[2][128]x2 @24576
//   P3 : hs f32[64][132] @byte0 | hos u16[64][72] @u16 17408 (persists)
//   PA/PB: Cs u16[2][8192] @0 | Dv f32[2][128] @u16 22016 | Sv f32[64] @u16 22528
__global__ __launch_bounds__(256, 2) void k_fused(
    const u16* __restrict__ adj_sw, const u16* __restrict__ suppT_sw,
    const float* __restrict__ bias, const float* __restrict__ gamma,
    const float* __restrict__ beta, const float* __restrict__ gWT,
    float* __restrict__ psum, float* __restrict__ psq,
    float* __restrict__ scaleB, float* __restrict__ shiftB,
    u16* __restrict__ hp_sw, float* __restrict__ iDbuf, float* __restrict__ out) {
  cg::grid_group gg = cg::this_grid();
  __shared__ __align__(16) u16 SB[25600];
  const int bx = blockIdx.x, by = blockIdx.y;
  const int t = threadIdx.x;
  const int w = t >> 6, l = t & 63;
  const int wm = w >> 1, wn = w & 1;
  const int lg = l >> 4, lr = l & 15;

  u16* As = SB;
  u16* Bs = SB + 8192;
  float* redS = (float*)(SB + 24576);  // [2][128]
  float* redQ = redS + 256;            // [2][128]

  // ---------------- Phase 1: GCN GEMM ----------------
  f32x4 acc[2][4];
#pragma unroll
  for (int mf = 0; mf < 2; ++mf)
#pragma unroll
    for (int nf = 0; nf < 4; ++nf) {
      acc[mf][nf][0] = 0.f; acc[mf][nf][1] = 0.f;
      acc[mf][nf][2] = 0.f; acc[mf][nf][3] = 0.f;
    }

#define GCN_STAGE(buf, kt)                                                        \
  {                                                                               \
    _Pragma("unroll") for (int i = 0; i < 2; ++i) {                               \
      const int s0 = i * 256 + w * 64;                                            \
      gload16(adj_sw + ((size_t)(bx * 32 + (kt))) * 4096 + (size_t)(s0 + l) * 8,  \
              &As[(buf)*4096 + s0 * 8]);                                          \
    }                                                                             \
    _Pragma("unroll") for (int i = 0; i < 4; ++i) {                               \
      const int s0 = i * 256 + w * 64;                                            \
      gload16(suppT_sw + ((size_t)(by * 32 + (kt))) * 8192 + (size_t)(s0 + l) * 8,\
              &Bs[(buf)*8192 + s0 * 8]);                                          \
    }                                                                             \
  }

  GCN_STAGE(0, 0);
  __syncthreads();
  for (int kt = 0; kt < 32; ++kt) {
    const int cur = kt & 1;
    if (kt + 1 < 32) GCN_STAGE(cur ^ 1, kt + 1);
#pragma unroll
    for (int kb = 0; kb < 2; ++kb) {
      const int ko = kb * 4 + lg;
      const bf16x8 a0 = *(const bf16x8*)&As[cur * 4096 + (ko * 64 + wm * 32 + lr) * 8];
      const bf16x8 a1 = *(const bf16x8*)&As[cur * 4096 + (ko * 64 + wm * 32 + 16 + lr) * 8];
      const bf16x8 b0 = *(const bf16x8*)&Bs[cur * 8192 + (ko * 128 + wn * 64 + lr) * 8];
      const bf16x8 b1 = *(const bf16x8*)&Bs[cur * 8192 + (ko * 128 + wn * 64 + 16 + lr) * 8];
      const bf16x8 b2 = *(const bf16x8*)&Bs[cur * 8192 + (ko * 128 + wn * 64 + 32 + lr) * 8];
      const bf16x8 b3 = *(const bf16x8*)&Bs[cur * 8192 + (ko * 128 + wn * 64 + 48 + lr) * 8];
      acc[0][0] = mfma16(a0, b0, acc[0][0]);
      acc[0][1] = mfma16(a0, b1, acc[0][1]);
      acc[0][2] = mfma16(a0, b2, acc[0][2]);
      acc[0][3] = mfma16(a0, b3, acc[0][3]);
      acc[1][0] = mfma16(a1, b0, acc[1][0]);
      acc[1][1] = mfma16(a1, b1, acc[1][1]);
      acc[1][2] = mfma16(a1, b2, acc[1][2]);
      acc[1][3] = mfma16(a1, b3, acc[1][3]);
    }
    __syncthreads();
  }
#undef GCN_STAGE
  // epilogue: bias into acc, BN partials
#pragma unroll
  for (int nf = 0; nf < 4; ++nf) {
    const int d = wn * 64 + nf * 16 + lr;
    const float bv = bias[d];
    float s = 0.f, q = 0.f;
#pragma unroll
    for (int mf = 0; mf < 2; ++mf)
#pragma unroll
      for (int r = 0; r < 4; ++r) {
        const float v = acc[mf][nf][r] + bv;
        acc[mf][nf][r] = v;
        s += v;
        q = fmaf(v, v, q);
      }
    s += __shfl_xor(s, 16);
    s += __shfl_xor(s, 32);
    q += __shfl_xor(q, 16);
    q += __shfl_xor(q, 32);
    if (lg == 0) {
      redS[wm * 128 + d] = s;
      redQ[wm * 128 + d] = q;
    }
  }
  __syncthreads();
  if (t < 128) {
    const int blk = by * 32 + bx;
    psum[blk * 128 + t] = redS[t] + redS[128 + t];
    psq[blk * 128 + t] = redQ[t] + redQ[128 + t];
  }
  gg.sync();

  // ---------------- Phase 2: BN finalize (blocks 0..127) ----------------
  {
    const int bid = by * 32 + bx;
    if (bid < 128) {
      const int d = bid;
      float s = psum[(size_t)t * 128 + d] + psum[(size_t)(t + 256) * 128 + d];
      float q = psq[(size_t)t * 128 + d] + psq[(size_t)(t + 256) * 128 + d];
#pragma unroll
      for (int o = 1; o < 64; o <<= 1) {
        s += __shfl_xor(s, o);
        q += __shfl_xor(q, o);
      }
      if (l == 0) {
        redS[w] = s;
        redQ[w] = q;
      }
      __syncthreads();
      if (t == 0) {
        const float ss = redS[0] + redS[1] + redS[2] + redS[3];
        const float qq = redQ[0] + redQ[1] + redQ[2] + redQ[3];
        const float inv = 1.f / (float)(NB * NN);
        const float mean = ss * inv;
        const float var = qq * inv - mean * mean;
        const float sc = gamma[d] * rsqrtf(var + 1e-5f);
        scaleB[d] = sc;
        shiftB[d] = beta[d] - mean * sc;
      }
    }
  }
  gg.sync();

  // ---------------- Phase 3: BN apply + relu + hp GEMM ----------------
  float* hs = (float*)SB;      // [64][132]
  u16* hos = SB + 17408;       // [64][72]
#pragma unroll
  for (int nf = 0; nf < 4; ++nf) {
    const int d = wn * 64 + nf * 16 + lr;
    const float sc = scaleB[d];
    const float sh2 = shiftB[d];
#pragma unroll
    for (int mf = 0; mf < 2; ++mf)
#pragma unroll
      for (int r = 0; r < 4; ++r) {
        const int row = wm * 32 + mf * 16 + lg * 4 + r;
        hs[row * 132 + d] = fmaxf(fmaf(acc[mf][nf][r], sc, sh2), 0.f);
      }
  }
  __syncthreads();
  {
    const int c = t & 63, q = t >> 6;
    float a2[16];
#pragma unroll
    for (int r = 0; r < 16; ++r) a2[r] = 0.f;
    for (int c4 = 0; c4 < 32; ++c4) {
      const float4 wv = *(const float4*)&gWT[c * 128 + c4 * 4];
#pragma unroll
      for (int r = 0; r < 16; ++r) {
        const float4 hv = *(const float4*)&hs[(q * 16 + r) * 132 + c4 * 4];
        a2[r] = fmaf(hv.x, wv.x, fmaf(hv.y, wv.y, fmaf(hv.z, wv.z, fmaf(hv.w, wv.w, a2[r]))));
      }
    }
    __syncthreads();  // hs dead; hos region disjoint but keep ordering clean
#pragma unroll
    for (int r = 0; r < 16; ++r) hos[(q * 16 + r) * 72 + c] = f2bf(a2[r]);
  }
  __syncthreads();
  {
    const size_t tbase = (size_t)(by * 32 + bx) * 4096;
#pragma unroll
    for (int k2 = 0; k2 < 2; ++k2) {
      const int s2 = t + k2 * 256;
      const int kb = s2 >> 6, r6 = s2 & 63;
      const uint2 lo = *(const uint2*)&hos[r6 * 72 + kb * 8];
      const uint2 hi = *(const uint2*)&hos[r6 * 72 + kb * 8 + 4];
      uint4 o;
      o.x = lo.x; o.y = lo.y; o.z = hi.x; o.w = hi.y;
      *(uint4*)&hp_sw[tbase + kb * 512 + r6 * 8] = o;
    }
  }
  gg.sync();

  // ---------------- Phase A: iD[n] = 1 / sum_m exp(lrelu(e)-30) ----------------
  u16* Cs = SB;  // [2][8192]
  const int b = by, n0 = bx << 6;
  const int qrow = (w << 4) + lr;
  const bf16x8 bq0 = *(const bf16x8*)&hos[qrow * 72 + lg * 8];
  const bf16x8 bq1 = *(const bf16x8*)&hos[qrow * 72 + (lg + 4) * 8];
#pragma unroll
  for (int i = 0; i < 4; ++i) {
    const int idx = w * 4 + i;
    gload16(hp_sw + (size_t)(b * 32 + (idx >> 3)) * 4096 + (size_t)((idx & 7) * 64 + l) * 8,
            &Cs[idx * 512]);
  }
  __syncthreads();
  float S = 0.f;
  for (int mt = 0; mt < 16; ++mt) {
    const int cur = mt & 1;
    if (mt + 1 < 16) {
#pragma unroll
      for (int i = 0; i < 4; ++i) {
        const int idx = w * 4 + i;
        gload16(hp_sw + (size_t)(b * 32 + (mt + 1) * 2 + (idx >> 3)) * 4096 +
                    (size_t)((idx & 7) * 64 + l) * 8,
                &Cs[(cur ^ 1) * 8192 + idx * 512]);
      }
    }
#pragma unroll
    for (int mf = 0; mf < 8; ++mf) {
      const int toff = cur * 8192 + (mf >> 2) * 4096;
      const int mloc = (mf & 3) * 16;
      const bf16x8 a0 = *(const bf16x8*)&Cs[toff + ((lg)*64 + mloc + lr) * 8];
      const bf16x8 a1 = *(const bf16x8*)&Cs[toff + ((lg + 4) * 64 + mloc + lr) * 8];
      f32x4 z;
      z[0] = 0.f; z[1] = 0.f; z[2] = 0.f; z[3] = 0.f;
      z = mfma16(a0, bq0, z);
      z = mfma16(a1, bq1, z);
      S += __expf(lrelu(z[0]) - 30.f) + __expf(lrelu(z[1]) - 30.f) +
           __expf(lrelu(z[2]) - 30.f) + __expf(lrelu(z[3]) - 30.f);
    }
    __syncthreads();
  }
  S += __shfl_xor(S, 16);
  S += __shfl_xor(S, 32);
  if (l < 16) iDbuf[b * NN + n0 + (w << 4) + l] = 1.f / S;
  gg.sync();

  // ---------------- Phase B: S[n] = sum_m exp(e-30)/D[m]; out = hp*S ----------------
  float* Dv = (float*)(SB + 22016);  // [2][128]
  float* Sv = (float*)(SB + 22528);  // [64]
#pragma unroll
  for (int i = 0; i < 4; ++i) {
    const int idx = w * 4 + i;
    gload16(hp_sw + (size_t)(b * 32 + (idx >> 3)) * 4096 + (size_t)((idx & 7) * 64 + l) * 8,
            &Cs[idx * 512]);
  }
  if (t < 128) Dv[t] = iDbuf[b * NN + t];
  __syncthreads();
  float S2 = 0.f;
  for (int mt = 0; mt < 16; ++mt) {
    const int cur = mt & 1;
    if (mt + 1 < 16) {
#pragma unroll
      for (int i = 0; i < 4; ++i) {
        const int idx = w * 4 + i;
        gload16(hp_sw + (size_t)(b * 32 + (mt + 1) * 2 + (idx >> 3)) * 4096 +
                    (size_t)((idx & 7) * 64 + l) * 8,
                &Cs[(cur ^ 1) * 8192 + idx * 512]);
      }
      if (t < 128) Dv[(cur ^ 1) * 128 + t] = iDbuf[b * NN + (mt + 1) * 128 + t];
    }
#pragma unroll
    for (int mf = 0; mf < 8; ++mf) {
      const int toff = cur * 8192 + (mf >> 2) * 4096;
      const int mloc = (mf & 3) * 16;
      const bf16x8 a0 = *(const bf16x8*)&Cs[toff + ((lg)*64 + mloc + lr) * 8];
      const bf16x8 a1 = *(const bf16x8*)&Cs[toff + ((lg + 4) * 64 + mloc + lr) * 8];
      f32x4 z;
      z[0] = 0.f; z[1] = 0.f; z[2] = 0.f; z[3] = 0.f;
      z = mfma16(a0, bq0, z);
      z = mfma16(a1, bq1, z);
      const float4 dv = *(const float4*)&Dv[cur * 128 + (mf >> 2) * 64 + (mf & 3) * 16 + lg * 4];
      S2 += __expf(lrelu(z[0]) - 30.f) * dv.x;
      S2 += __expf(lrelu(z[1]) - 30.f) * dv.y;
      S2 += __expf(lrelu(z[2]) - 30.f) * dv.z;
      S2 += __expf(lrelu(z[3]) - 30.f) * dv.w;
    }
    __syncthreads();
  }
  S2 += __shfl_xor(S2, 16);
  S2 += __shfl_xor(S2, 32);
  if (l < 16) Sv[(w << 4) + l] = S2;
  __syncthreads();
  {
    const int row = t >> 2;
    const float sc = Sv[row];
    const size_t R = (size_t)b * NN + n0 + row;
#pragma unroll
    for (int hh = 0; hh < 2; ++hh) {
      const int kb = (t & 3) * 2 + hh;
      const u16* src = &hos[row * 72 + kb * 8];
      float4 o0, o1;
      o0.x = bf2f(src[0]) * sc;
      o0.y = bf2f(src[1]) * sc;
      o0.z = bf2f(src[2]) * sc;
      o0.w = bf2f(src[3]) * sc;
      o1.x = bf2f(src[4]) * sc;
      o1.y = bf2f(src[5]) * sc;
      o1.z = bf2f(src[6]) * sc;
      o1.w = bf2f(src[7]) * sc;
      *(float4*)&out[R * NO + kb * 8] = o0;
      *(float4*)&out[R * NO + kb * 8 + 4] = o1;
    }
  }
}

extern "C" void kernel_launch(void* const* d_in, const int* in_sizes, int n_in,
                              void* d_out, int out_size, void* d_ws, size_t ws_size,
                              hipStream_t stream) {
  const float* x = (const float*)d_in[0];
  // d_in[1] = adj (unused)
  const float* adj_gcn = (const float*)d_in[2];
  const float* gcn_w = (const float*)d_in[3];
  const float* gcn_b = (const float*)d_in[4];
  const float* gamma = (const float*)d_in[5];
  const float* beta = (const float*)d_in[6];
  const float* gat_w = (const float*)d_in[7];
  float* out = (float*)d_out;
  float* ws = (float*)d_ws;

  // workspace layout (float units), peak ~8.3M floats (33MB):
  u16* adj_sw = (u16*)ws;                 // [0, 2M)
  u16* suppT_sw = (u16*)(ws + 2097152);   // [2M, 4M)
  u16* x_sw = (u16*)(ws + 4194304);       // [4M, 6M)
  u16* hp_sw = (u16*)(ws + 6291456);      // [6M, 8M)
  float* iDbuf = ws + 8388608;            // 32768
  float* psum = iDbuf + 32768;            // 65536
  float* psq = psum + 65536;              // 65536
  float* scale = psq + 65536;             // 128
  float* shift = scale + 128;             // 128
  float* gWT = shift + 128;               // 8192
  u16* Wsw = (u16*)(gWT + 8192);          // 16384 u16

  k_prep<<<dim3(1289), dim3(256), 0, stream>>>(x, adj_gcn, gcn_w, gat_w, x_sw, adj_sw, gWT, Wsw);
  k_support<<<dim3(256), dim3(256), 0, stream>>>(x_sw, Wsw, suppT_sw);

  void* kargs[] = {(void*)&adj_sw, (void*)&suppT_sw, (void*)&gcn_b, (void*)&gamma,
                   (void*)&beta,   (void*)&gWT,      (void*)&psum,  (void*)&psq,
                   (void*)&scale,  (void*)&shift,    (void*)&hp_sw, (void*)&iDbuf,
                   (void*)&out};
  hipLaunchCooperativeKernel((void*)k_fused, dim3(32, 16), dim3(256), kargs, 0, stream);
}

// Round 7
// 159.931 us; speedup vs baseline: 2.0207x; 2.0207x over previous
//
#include <hip/hip_runtime.h>
#include <math.h>

#define NB 16
#define NN 2048
#define NF 128
#define NH 128
#define NO 64

typedef short bf16x8 __attribute__((ext_vector_type(8)));
typedef float f32x4 __attribute__((ext_vector_type(4)));
typedef unsigned short u16;
typedef unsigned int u32;

#define LOG2E 1.4426950408889634f
#define EXPSHIFT 43.28085122666891f  // 30 * log2(e)

__device__ __forceinline__ u16 f2bf(float f) {
  u32 u = __builtin_bit_cast(u32, f);
  return (u16)((u + 0x7fffu + ((u >> 16) & 1u)) >> 16);
}
__device__ __forceinline__ float bf2f(u16 h) {
  u32 u = ((u32)h) << 16;
  return __builtin_bit_cast(float, u);
}

__device__ __forceinline__ void gload16(const void* g, void* l) {
  __builtin_amdgcn_global_load_lds((const __attribute__((address_space(1))) void*)g,
                                   (__attribute__((address_space(3))) void*)l, 16, 0, 0);
}
__device__ __forceinline__ f32x4 mfma16(bf16x8 a, bf16x8 b, f32x4 c) {
  return __builtin_amdgcn_mfma_f32_16x16x32_bf16(a, b, c, 0, 0, 0);
}
// exp(lrelu(z) - 30) with 4 VALU ops: max, mul(0.2z), fma, v_exp
__device__ __forceinline__ float explr(float z) {
  return __builtin_amdgcn_exp2f(fmaf(fmaxf(z, 0.2f * z), LOG2E, -EXPSHIFT));
}

// ---------------- K_prep: all input preprocessing in one kernel --------------
// bid 0      : gWT[c][k] = gat_w[k][c] (fp32)
// bid 1..8   : Wsw  = gcn_w bf16 in [kblk 16][d 128][8] image
// bid 9..264 : x_sw = x bf16 in [rowblk 256][kblk 16][row 128][8] image
// bid 265..  : adj_sw = adj bf16 in [ntile 32][ktile 32][kblk 8][row 64][8] image
__global__ __launch_bounds__(256) void k_prep(const float* __restrict__ x,
                                              const float* __restrict__ adj,
                                              const float* __restrict__ gcn_w,
                                              const float* __restrict__ gat_w,
                                              u16* __restrict__ x_sw,
                                              u16* __restrict__ adj_sw,
                                              float* __restrict__ gWT,
                                              u16* __restrict__ Wsw) {
  __shared__ u16 ts[128 * 136];
  const int t = threadIdx.x;
  const int bid = blockIdx.x;
  if (bid == 0) {
    const int c = t & 63, kq = t >> 6;
    for (int k = kq * 32; k < kq * 32 + 32; ++k) gWT[c * 128 + k] = gat_w[k * 64 + c];
  } else if (bid < 9) {
    const int s = (bid - 1) * 256 + t;  // [kb 16][d 128]
    const int kb = s >> 7, d = s & 127;
    u16 tmp[8];
#pragma unroll
    for (int j = 0; j < 8; ++j) tmp[j] = f2bf(gcn_w[(kb * 8 + j) * 128 + d]);
    uint4 o;
    o.x = (u32)tmp[0] | ((u32)tmp[1] << 16);
    o.y = (u32)tmp[2] | ((u32)tmp[3] << 16);
    o.z = (u32)tmp[4] | ((u32)tmp[5] << 16);
    o.w = (u32)tmp[6] | ((u32)tmp[7] << 16);
    *(uint4*)&Wsw[(size_t)s * 8] = o;
  } else if (bid < 265) {
    const int blk = bid - 9;  // 128 rows of x
    const size_t r0 = (size_t)blk * 128;
#pragma unroll
    for (int k = 0; k < 16; ++k) {
      const int s = t + k * 256;  // 4096 float4 slots
      const int row = s >> 5, c4 = (s & 31) * 4;
      const float4 f = *(const float4*)&x[(r0 + row) * 128 + c4];
      uint2 pk;
      pk.x = (u32)f2bf(f.x) | ((u32)f2bf(f.y) << 16);
      pk.y = (u32)f2bf(f.z) | ((u32)f2bf(f.w) << 16);
      *(uint2*)&ts[row * 136 + c4] = pk;
    }
    __syncthreads();
#pragma unroll
    for (int k = 0; k < 8; ++k) {
      const int s = t + k * 256;  // 2048 16B slots: [kb 16][row 128]
      const int kb = s >> 7, row = s & 127;
      const uint4 v = *(const uint4*)&ts[row * 136 + kb * 8];
      *(uint4*)&x_sw[(size_t)blk * 16384 + (size_t)s * 8] = v;
    }
  } else {
    const int tile = bid - 265;  // 64x64 tile of adj: [nt 32][kt 32]
    const int n0 = (tile >> 5) * 64, m0 = (tile & 31) * 64;
#pragma unroll
    for (int k = 0; k < 4; ++k) {
      const int s = t + k * 256;  // 1024 float4 slots
      const int row = s >> 4, c4 = (s & 15) * 4;
      const float4 f = *(const float4*)&adj[(size_t)(n0 + row) * 2048 + m0 + c4];
      uint2 pk;
      pk.x = (u32)f2bf(f.x) | ((u32)f2bf(f.y) << 16);
      pk.y = (u32)f2bf(f.z) | ((u32)f2bf(f.w) << 16);
      *(uint2*)&ts[row * 136 + c4] = pk;
    }
    __syncthreads();
#pragma unroll
    for (int k = 0; k < 2; ++k) {
      const int s = t + k * 256;  // 512 16B slots: [kb 8][row 64]
      const int kb = s >> 6, row = s & 63;
      const uint4 v = *(const uint4*)&ts[row * 136 + kb * 8];
      *(uint4*)&adj_sw[(size_t)tile * 4096 + (size_t)s * 8] = v;
    }
  }
}

// ---------------- K_support: suppT_sw = (x @ W)^T, pre-swizzled bf16 ---------
__global__ __launch_bounds__(256) void k_support(const u16* __restrict__ x_sw,
                                                 const u16* __restrict__ Wsw,
                                                 u16* __restrict__ suppT_sw) {
  const int m0g = blockIdx.x * 128;
  const int t = threadIdx.x, w = t >> 6, l = t & 63;
  const int lg = l >> 4, lr = l & 15;
  __shared__ __align__(16) u16 sh[32768];  // 64KB stage; reused as os
  u16* As = sh;
  u16* Bs = sh + 16384;
#pragma unroll
  for (int i = 0; i < 8; ++i) {
    const int s0 = i * 256 + w * 64;
    gload16(x_sw + (size_t)blockIdx.x * 16384 + (size_t)(s0 + l) * 8, &As[(size_t)s0 * 8]);
  }
#pragma unroll
  for (int i = 0; i < 8; ++i) {
    const int s0 = i * 256 + w * 64;
    gload16(Wsw + (size_t)(s0 + l) * 8, &Bs[(size_t)s0 * 8]);
  }
  __syncthreads();
  f32x4 acc[2][8];
#pragma unroll
  for (int mf = 0; mf < 2; ++mf)
#pragma unroll
    for (int nf = 0; nf < 8; ++nf) {
      acc[mf][nf][0] = 0.f; acc[mf][nf][1] = 0.f;
      acc[mf][nf][2] = 0.f; acc[mf][nf][3] = 0.f;
    }
#pragma unroll
  for (int ks = 0; ks < 4; ++ks) {
    const int kb = ks * 4 + lg;
    const bf16x8 a0 = *(const bf16x8*)&As[((size_t)kb * 128 + w * 32 + lr) * 8];
    const bf16x8 a1 = *(const bf16x8*)&As[((size_t)kb * 128 + w * 32 + 16 + lr) * 8];
#pragma unroll
    for (int nf = 0; nf < 8; ++nf) {
      const bf16x8 b = *(const bf16x8*)&Bs[((size_t)kb * 128 + nf * 16 + lr) * 8];
      acc[0][nf] = mfma16(a0, b, acc[0][nf]);
      acc[1][nf] = mfma16(a1, b, acc[1][nf]);
    }
  }
  __syncthreads();
  u16* os = sh;  // transpose: os[d][m_local], stride 136 u16
#pragma unroll
  for (int nf = 0; nf < 8; ++nf) {
    const int d = nf * 16 + lr;
#pragma unroll
    for (int mf = 0; mf < 2; ++mf) {
      const int mb = w * 32 + mf * 16 + lg * 4;
      const u32 p0 = (u32)f2bf(acc[mf][nf][0]) | ((u32)f2bf(acc[mf][nf][1]) << 16);
      const u32 p1 = (u32)f2bf(acc[mf][nf][2]) | ((u32)f2bf(acc[mf][nf][3]) << 16);
      *(u32*)&os[d * 136 + mb] = p0;
      *(u32*)&os[d * 136 + mb + 2] = p1;
    }
  }
  __syncthreads();
  const int b = m0g >> 11, mt0 = (m0g & 2047) >> 6;
#pragma unroll
  for (int i = 0; i < 8; ++i) {
    const int s = i * 256 + t;  // [kt 2][kb 8][d 128]
    const int kt = s >> 10, kb = (s >> 7) & 7, d = s & 127;
    const uint4 v = *(const uint4*)&os[d * 136 + kt * 64 + kb * 8];
    *(uint4*)&suppT_sw[((size_t)((b * 32 + mt0 + kt) * 8 + kb)) * 1024 + (size_t)d * 8] = v;
  }
}

// ---------------- K_gcn: h = adj @ supp + bias (+ fused BN partials) ---------
__global__ __launch_bounds__(256) void k_gcn(const u16* __restrict__ adj_sw,
                                             const u16* __restrict__ suppT_sw,
                                             const float* __restrict__ bias,
                                             float* __restrict__ h,
                                             float* __restrict__ psum,
                                             float* __restrict__ psq) {
  const int nt = blockIdx.x;
  const int b = blockIdx.y;
  const int n0 = nt * 64;
  const int t = threadIdx.x;
  const int w = t >> 6, l = t & 63;
  const int wm = w >> 1, wn = w & 1;
  const int lg = l >> 4, lr = l & 15;
  __shared__ __align__(16) u16 As[2][4096];  // [8 kblk][64 row][8]
  __shared__ __align__(16) u16 Bs[2][8192];  // [8 kblk][128 d][8]
  __shared__ float redS[2][128], redQ[2][128];

  f32x4 acc[2][4];
#pragma unroll
  for (int mf = 0; mf < 2; ++mf)
#pragma unroll
    for (int nf = 0; nf < 4; ++nf) {
      acc[mf][nf][0] = 0.f; acc[mf][nf][1] = 0.f;
      acc[mf][nf][2] = 0.f; acc[mf][nf][3] = 0.f;
    }

#define GCN_STAGE(buf, kt)                                                       \
  {                                                                              \
    _Pragma("unroll") for (int i = 0; i < 2; ++i) {                              \
      const int s0 = i * 256 + w * 64;                                           \
      gload16(adj_sw + ((size_t)(nt * 32 + (kt))) * 4096 + (size_t)(s0 + l) * 8, \
              &As[buf][s0 * 8]);                                                 \
    }                                                                            \
    _Pragma("unroll") for (int i = 0; i < 4; ++i) {                              \
      const int s0 = i * 256 + w * 64;                                           \
      gload16(suppT_sw + ((size_t)(b * 32 + (kt))) * 8192 + (size_t)(s0 + l) * 8,\
              &Bs[buf][s0 * 8]);                                                 \
    }                                                                            \
  }

  GCN_STAGE(0, 0);
  __syncthreads();
  for (int kt = 0; kt < 32; ++kt) {
    const int cur = kt & 1;
    if (kt + 1 < 32) GCN_STAGE(cur ^ 1, kt + 1);
#pragma unroll
    for (int kb = 0; kb < 2; ++kb) {
      const int ko = kb * 4 + lg;
      const bf16x8 a0 = *(const bf16x8*)&As[cur][(ko * 64 + wm * 32 + lr) * 8];
      const bf16x8 a1 = *(const bf16x8*)&As[cur][(ko * 64 + wm * 32 + 16 + lr) * 8];
      const bf16x8 b0 = *(const bf16x8*)&Bs[cur][(ko * 128 + wn * 64 + lr) * 8];
      const bf16x8 b1 = *(const bf16x8*)&Bs[cur][(ko * 128 + wn * 64 + 16 + lr) * 8];
      const bf16x8 b2 = *(const bf16x8*)&Bs[cur][(ko * 128 + wn * 64 + 32 + lr) * 8];
      const bf16x8 b3 = *(const bf16x8*)&Bs[cur][(ko * 128 + wn * 64 + 48 + lr) * 8];
      acc[0][0] = mfma16(a0, b0, acc[0][0]);
      acc[0][1] = mfma16(a0, b1, acc[0][1]);
      acc[0][2] = mfma16(a0, b2, acc[0][2]);
      acc[0][3] = mfma16(a0, b3, acc[0][3]);
      acc[1][0] = mfma16(a1, b0, acc[1][0]);
      acc[1][1] = mfma16(a1, b1, acc[1][1]);
      acc[1][2] = mfma16(a1, b2, acc[1][2]);
      acc[1][3] = mfma16(a1, b3, acc[1][3]);
    }
    __syncthreads();
  }
#undef GCN_STAGE
#pragma unroll
  for (int nf = 0; nf < 4; ++nf) {
    const int d = wn * 64 + nf * 16 + lr;
    const float bv = bias[d];
    float s = 0.f, q = 0.f;
#pragma unroll
    for (int mf = 0; mf < 2; ++mf) {
#pragma unroll
      for (int r = 0; r < 4; ++r) {
        const float v = acc[mf][nf][r] + bv;
        const int row = n0 + wm * 32 + mf * 16 + lg * 4 + r;
        h[((size_t)(b * NN + row)) * NH + d] = v;
        s += v;
        q = fmaf(v, v, q);
      }
    }
    s += __shfl_xor(s, 16);
    s += __shfl_xor(s, 32);
    q += __shfl_xor(q, 16);
    q += __shfl_xor(q, 32);
    if (lg == 0) {
      redS[wm][d] = s;
      redQ[wm][d] = q;
    }
  }
  __syncthreads();
  if (t < 128) {
    const int blk = b * 32 + nt;
    psum[blk * 128 + t] = redS[0][t] + redS[1][t];
    psq[blk * 128 + t] = redQ[0][t] + redQ[1][t];
  }
}

// ---------------- BN finalize (512 partials) ---------------------------------
__global__ __launch_bounds__(1024) void k_bnstat2(const float* __restrict__ psum,
                                                  const float* __restrict__ psq,
                                                  const float* __restrict__ gamma,
                                                  const float* __restrict__ beta,
                                                  float* __restrict__ scale,
                                                  float* __restrict__ shift) {
  const int t = threadIdx.x;
  const int d = t & 127;
  const int g = t >> 7;
  float s = 0.f, q = 0.f;
  for (int i = g; i < 512; i += 8) {
    s += psum[i * 128 + d];
    q += psq[i * 128 + d];
  }
  __shared__ float ls[8][128], lq[8][128];
  ls[g][d] = s;
  lq[g][d] = q;
  __syncthreads();
  if (t < 128) {
    s = 0.f;
    q = 0.f;
#pragma unroll
    for (int i = 0; i < 8; ++i) {
      s += ls[i][t];
      q += lq[i][t];
    }
    const float inv = 1.f / (float)(NB * NN);
    const float mean = s * inv;
    const float var = q * inv - mean * mean;
    const float sc = gamma[t] * rsqrtf(var + 1e-5f);
    scale[t] = sc;
    shift[t] = beta[t] - mean * sc;
  }
}

// ---------------- K_hp: hp = relu(bn(h)) @ gat_W, pre-swizzled bf16 ----------
__global__ __launch_bounds__(256) void k_hp(const float* __restrict__ h,
                                            const float* __restrict__ scale,
                                            const float* __restrict__ shift,
                                            const float* __restrict__ gWT,
                                            u16* __restrict__ hp_sw) {
  const int row0 = blockIdx.x * 64;
  __shared__ float hs[64][132];
  __shared__ __align__(16) u16 hos[64][72];
  const int t = threadIdx.x;
#pragma unroll
  for (int k = 0; k < 8; ++k) {
    const int s = t + k * 256;
    const int row = s >> 5, c4 = (s & 31) * 4;
    const float4 v = *(const float4*)&h[(size_t)(row0 + row) * NH + c4];
    const float4 sc = *(const float4*)&scale[c4];
    const float4 sh = *(const float4*)&shift[c4];
    hs[row][c4 + 0] = fmaxf(fmaf(v.x, sc.x, sh.x), 0.f);
    hs[row][c4 + 1] = fmaxf(fmaf(v.y, sc.y, sh.y), 0.f);
    hs[row][c4 + 2] = fmaxf(fmaf(v.z, sc.z, sh.z), 0.f);
    hs[row][c4 + 3] = fmaxf(fmaf(v.w, sc.w, sh.w), 0.f);
  }
  __syncthreads();
  const int c = t & 63, q = t >> 6;
  float acc[16];
#pragma unroll
  for (int r = 0; r < 16; ++r) acc[r] = 0.f;
  for (int c4 = 0; c4 < 32; ++c4) {
    const float4 wv = *(const float4*)&gWT[c * 128 + c4 * 4];
#pragma unroll
    for (int r = 0; r < 16; ++r) {
      const float4 hv = *(const float4*)&hs[q * 16 + r][c4 * 4];
      acc[r] = fmaf(hv.x, wv.x, fmaf(hv.y, wv.y, fmaf(hv.z, wv.z, fmaf(hv.w, wv.w, acc[r]))));
    }
  }
#pragma unroll
  for (int r = 0; r < 16; ++r) hos[q * 16 + r][c] = f2bf(acc[r]);
  __syncthreads();
  const size_t tbase = (size_t)blockIdx.x * 4096;
#pragma unroll
  for (int k = 0; k < 2; ++k) {
    const int s = t + k * 256;
    const int kb = s >> 6, r6 = s & 63;
    const uint2 lo = *(const uint2*)&hos[r6][kb * 8];
    const uint2 hi = *(const uint2*)&hos[r6][kb * 8 + 4];
    uint4 o;
    o.x = lo.x; o.y = lo.y; o.z = hi.x; o.w = hi.y;
    *(uint4*)&hp_sw[tbase + kb * 512 + r6 * 8] = o;
  }
}

// ---------------- K_attnA: iD[n] = 1/sum_m exp(lrelu(e)-30) ------------------
// No LDS, no barriers: A-fragments read straight from hp_sw (L2-resident).
__global__ __launch_bounds__(256) void k_attnA(const u16* __restrict__ hp_sw,
                                               float* __restrict__ iDbuf) {
  const int b = blockIdx.x >> 5;
  const int nt = blockIdx.x & 31;
  const int t = threadIdx.x, w = t >> 6, l = t & 63;
  const int lg = l >> 4, lr = l & 15;
  const u16* rbase = hp_sw + (size_t)(b * 32 + nt) * 4096;
  const int qrow = (w << 4) + lr;
  const bf16x8 bq0 = *(const bf16x8*)&rbase[(lg * 64 + qrow) * 8];
  const bf16x8 bq1 = *(const bf16x8*)&rbase[((lg + 4) * 64 + qrow) * 8];
  const u16* cb = hp_sw + (size_t)b * 32 * 4096;
  float S = 0.f;
  for (int mt = 0; mt < 32; ++mt) {
    const u16* base = cb + (size_t)mt * 4096;
#pragma unroll
    for (int mf = 0; mf < 4; ++mf) {
      const bf16x8 a0 = *(const bf16x8*)&base[(lg * 64 + mf * 16 + lr) * 8];
      const bf16x8 a1 = *(const bf16x8*)&base[((lg + 4) * 64 + mf * 16 + lr) * 8];
      f32x4 z;
      z[0] = 0.f; z[1] = 0.f; z[2] = 0.f; z[3] = 0.f;
      z = mfma16(a0, bq0, z);
      z = mfma16(a1, bq1, z);
      S += explr(z[0]) + explr(z[1]) + explr(z[2]) + explr(z[3]);
    }
  }
  S += __shfl_xor(S, 16);
  S += __shfl_xor(S, 32);
  if (l < 16) iDbuf[b * NN + nt * 64 + qrow] = 1.f / S;
}

// ---------------- K_attnB: S[n] = sum_m exp(e-30)*iD[m]; out = hp*S ----------
__global__ __launch_bounds__(256) void k_attnB(const u16* __restrict__ hp_sw,
                                               const float* __restrict__ iDbuf,
                                               float* __restrict__ out) {
  const int b = blockIdx.x >> 5;
  const int nt = blockIdx.x & 31;
  const int n0 = nt << 6;
  const int t = threadIdx.x, w = t >> 6, l = t & 63;
  const int lg = l >> 4, lr = l & 15;
  __shared__ float Sv[64];
  const u16* rbase = hp_sw + (size_t)(b * 32 + nt) * 4096;
  const int qrow = (w << 4) + lr;
  const bf16x8 bq0 = *(const bf16x8*)&rbase[(lg * 64 + qrow) * 8];
  const bf16x8 bq1 = *(const bf16x8*)&rbase[((lg + 4) * 64 + qrow) * 8];
  const u16* cb = hp_sw + (size_t)b * 32 * 4096;
  const float* dbase = iDbuf + b * NN;
  float S = 0.f;
  for (int mt = 0; mt < 32; ++mt) {
    const u16* base = cb + (size_t)mt * 4096;
#pragma unroll
    for (int mf = 0; mf < 4; ++mf) {
      const bf16x8 a0 = *(const bf16x8*)&base[(lg * 64 + mf * 16 + lr) * 8];
      const bf16x8 a1 = *(const bf16x8*)&base[((lg + 4) * 64 + mf * 16 + lr) * 8];
      f32x4 z;
      z[0] = 0.f; z[1] = 0.f; z[2] = 0.f; z[3] = 0.f;
      z = mfma16(a0, bq0, z);
      z = mfma16(a1, bq1, z);
      const float4 dv = *(const float4*)&dbase[mt * 64 + mf * 16 + lg * 4];
      S = fmaf(explr(z[0]), dv.x, S);
      S = fmaf(explr(z[1]), dv.y, S);
      S = fmaf(explr(z[2]), dv.z, S);
      S = fmaf(explr(z[3]), dv.w, S);
    }
  }
  S += __shfl_xor(S, 16);
  S += __shfl_xor(S, 32);
  if (l < 16) Sv[qrow] = S;
  __syncthreads();
  const int row = t >> 2;
  const float sc = Sv[row];
  const size_t R = (size_t)b * NN + n0 + row;
#pragma unroll
  for (int hh = 0; hh < 2; ++hh) {
    const int kb = (t & 3) * 2 + hh;
    const u16* src = &rbase[(kb * 64 + row) * 8];
    float4 o0, o1;
    o0.x = bf2f(src[0]) * sc;
    o0.y = bf2f(src[1]) * sc;
    o0.z = bf2f(src[2]) * sc;
    o0.w = bf2f(src[3]) * sc;
    o1.x = bf2f(src[4]) * sc;
    o1.y = bf2f(src[5]) * sc;
    o1.z = bf2f(src[6]) * sc;
    o1.w = bf2f(src[7]) * sc;
    *(float4*)&out[R * NO + kb * 8] = o0;
    *(float4*)&out[R * NO + kb * 8 + 4] = o1;
  }
}

extern "C" void kernel_launch(void* const* d_in, const int* in_sizes, int n_in,
                              void* d_out, int out_size, void* d_ws, size_t ws_size,
                              hipStream_t stream) {
  const float* x = (const float*)d_in[0];
  // d_in[1] = adj (unused)
  const float* adj_gcn = (const float*)d_in[2];
  const float* gcn_w = (const float*)d_in[3];
  const float* gcn_b = (const float*)d_in[4];
  const float* gamma = (const float*)d_in[5];
  const float* beta = (const float*)d_in[6];
  const float* gat_w = (const float*)d_in[7];
  float* out = (float*)d_out;
  float* ws = (float*)d_ws;

  // workspace layout (float units):
  u16* adj_sw = (u16*)ws;                  // [0, 2M) floats
  u16* suppT_sw = (u16*)(ws + 2097152);    // [2M, 4M)
  float* hbuf = ws + 4194304;              // [4M, 8M)
  u16* x_sw = (u16*)(ws + 4194304);        // aliases hbuf lower half (dead first)
  u16* hp_sw = (u16*)(ws + 8388608);       // [8M, 9M)
  float* iDbuf = ws + 9437184;             // 32768
  float* psum = iDbuf + 32768;             // 65536
  float* psq = psum + 65536;               // 65536
  float* scale = psq + 65536;              // 128
  float* shift = scale + 128;              // 128
  float* gWT = shift + 128;                // 8192
  u16* Wsw = (u16*)(gWT + 8192);           // 16384 u16

  k_prep<<<dim3(1289), dim3(256), 0, stream>>>(x, adj_gcn, gcn_w, gat_w, x_sw, adj_sw, gWT, Wsw);
  k_support<<<dim3(256), dim3(256), 0, stream>>>(x_sw, Wsw, suppT_sw);
  k_gcn<<<dim3(32, 16), dim3(256), 0, stream>>>(adj_sw, suppT_sw, gcn_b, hbuf, psum, psq);
  k_bnstat2<<<dim3(1), dim3(1024), 0, stream>>>(psum, psq, gamma, beta, scale, shift);
  k_hp<<<dim3(512), dim3(256), 0, stream>>>(hbuf, scale, shift, gWT, hp_sw);
  k_attnA<<<dim3(NB * 32), dim3(256), 0, stream>>>(hp_sw, iDbuf);
  k_attnB<<<dim3(NB * 32), dim3(256), 0, stream>>>(hp_sw, iDbuf, out);
}

// Round 8
// 131.010 us; speedup vs baseline: 2.4668x; 1.2208x over previous
//
#include <hip/hip_runtime.h>
#include <math.h>

#define NB 16
#define NN 2048
#define NF 128
#define NH 128
#define NO 64

typedef short bf16x8 __attribute__((ext_vector_type(8)));
typedef float f32x4 __attribute__((ext_vector_type(4)));
typedef unsigned short u16;
typedef unsigned int u32;

#define LOG2E 1.4426950408889634f
#define EXPSHIFT 43.28085122666891f  // 30 * log2(e)

__device__ __forceinline__ u16 f2bf(float f) {
  u32 u = __builtin_bit_cast(u32, f);
  return (u16)((u + 0x7fffu + ((u >> 16) & 1u)) >> 16);
}
__device__ __forceinline__ float bf2f(u16 h) {
  u32 u = ((u32)h) << 16;
  return __builtin_bit_cast(float, u);
}

__device__ __forceinline__ void gload16(const void* g, void* l) {
  __builtin_amdgcn_global_load_lds((const __attribute__((address_space(1))) void*)g,
                                   (__attribute__((address_space(3))) void*)l, 16, 0, 0);
}
__device__ __forceinline__ f32x4 mfma16(bf16x8 a, bf16x8 b, f32x4 c) {
  return __builtin_amdgcn_mfma_f32_16x16x32_bf16(a, b, c, 0, 0, 0);
}
// exp(lrelu(z) - 30): max, mul, fma, v_exp
__device__ __forceinline__ float explr(float z) {
  return __builtin_amdgcn_exp2f(fmaf(fmaxf(z, 0.2f * z), LOG2E, -EXPSHIFT));
}

// ---------------- K_prep -----------------------------------------------------
__global__ __launch_bounds__(256) void k_prep(const float* __restrict__ x,
                                              const float* __restrict__ adj,
                                              const float* __restrict__ gcn_w,
                                              const float* __restrict__ gat_w,
                                              u16* __restrict__ x_sw,
                                              u16* __restrict__ adj_sw,
                                              float* __restrict__ gWT,
                                              u16* __restrict__ Wsw) {
  __shared__ u16 ts[128 * 136];
  const int t = threadIdx.x;
  const int bid = blockIdx.x;
  if (bid == 0) {
    const int c = t & 63, kq = t >> 6;
    for (int k = kq * 32; k < kq * 32 + 32; ++k) gWT[c * 128 + k] = gat_w[k * 64 + c];
  } else if (bid < 9) {
    const int s = (bid - 1) * 256 + t;
    const int kb = s >> 7, d = s & 127;
    u16 tmp[8];
#pragma unroll
    for (int j = 0; j < 8; ++j) tmp[j] = f2bf(gcn_w[(kb * 8 + j) * 128 + d]);
    uint4 o;
    o.x = (u32)tmp[0] | ((u32)tmp[1] << 16);
    o.y = (u32)tmp[2] | ((u32)tmp[3] << 16);
    o.z = (u32)tmp[4] | ((u32)tmp[5] << 16);
    o.w = (u32)tmp[6] | ((u32)tmp[7] << 16);
    *(uint4*)&Wsw[(size_t)s * 8] = o;
  } else if (bid < 265) {
    const int blk = bid - 9;
    const size_t r0 = (size_t)blk * 128;
#pragma unroll
    for (int k = 0; k < 16; ++k) {
      const int s = t + k * 256;
      const int row = s >> 5, c4 = (s & 31) * 4;
      const float4 f = *(const float4*)&x[(r0 + row) * 128 + c4];
      uint2 pk;
      pk.x = (u32)f2bf(f.x) | ((u32)f2bf(f.y) << 16);
      pk.y = (u32)f2bf(f.z) | ((u32)f2bf(f.w) << 16);
      *(uint2*)&ts[row * 136 + c4] = pk;
    }
    __syncthreads();
#pragma unroll
    for (int k = 0; k < 8; ++k) {
      const int s = t + k * 256;
      const int kb = s >> 7, row = s & 127;
      const uint4 v = *(const uint4*)&ts[row * 136 + kb * 8];
      *(uint4*)&x_sw[(size_t)blk * 16384 + (size_t)s * 8] = v;
    }
  } else {
    const int tile = bid - 265;
    const int n0 = (tile >> 5) * 64, m0 = (tile & 31) * 64;
#pragma unroll
    for (int k = 0; k < 4; ++k) {
      const int s = t + k * 256;
      const int row = s >> 4, c4 = (s & 15) * 4;
      const float4 f = *(const float4*)&adj[(size_t)(n0 + row) * 2048 + m0 + c4];
      uint2 pk;
      pk.x = (u32)f2bf(f.x) | ((u32)f2bf(f.y) << 16);
      pk.y = (u32)f2bf(f.z) | ((u32)f2bf(f.w) << 16);
      *(uint2*)&ts[row * 136 + c4] = pk;
    }
    __syncthreads();
#pragma unroll
    for (int k = 0; k < 2; ++k) {
      const int s = t + k * 256;
      const int kb = s >> 6, row = s & 63;
      const uint4 v = *(const uint4*)&ts[row * 136 + kb * 8];
      *(uint4*)&adj_sw[(size_t)tile * 4096 + (size_t)s * 8] = v;
    }
  }
}

// ---------------- K_support --------------------------------------------------
__global__ __launch_bounds__(256) void k_support(const u16* __restrict__ x_sw,
                                                 const u16* __restrict__ Wsw,
                                                 u16* __restrict__ suppT_sw) {
  const int m0g = blockIdx.x * 128;
  const int t = threadIdx.x, w = t >> 6, l = t & 63;
  const int lg = l >> 4, lr = l & 15;
  __shared__ __align__(16) u16 sh[32768];
  u16* As = sh;
  u16* Bs = sh + 16384;
#pragma unroll
  for (int i = 0; i < 8; ++i) {
    const int s0 = i * 256 + w * 64;
    gload16(x_sw + (size_t)blockIdx.x * 16384 + (size_t)(s0 + l) * 8, &As[(size_t)s0 * 8]);
  }
#pragma unroll
  for (int i = 0; i < 8; ++i) {
    const int s0 = i * 256 + w * 64;
    gload16(Wsw + (size_t)(s0 + l) * 8, &Bs[(size_t)s0 * 8]);
  }
  __syncthreads();
  f32x4 acc[2][8];
#pragma unroll
  for (int mf = 0; mf < 2; ++mf)
#pragma unroll
    for (int nf = 0; nf < 8; ++nf) {
      acc[mf][nf][0] = 0.f; acc[mf][nf][1] = 0.f;
      acc[mf][nf][2] = 0.f; acc[mf][nf][3] = 0.f;
    }
#pragma unroll
  for (int ks = 0; ks < 4; ++ks) {
    const int kb = ks * 4 + lg;
    const bf16x8 a0 = *(const bf16x8*)&As[((size_t)kb * 128 + w * 32 + lr) * 8];
    const bf16x8 a1 = *(const bf16x8*)&As[((size_t)kb * 128 + w * 32 + 16 + lr) * 8];
#pragma unroll
    for (int nf = 0; nf < 8; ++nf) {
      const bf16x8 b = *(const bf16x8*)&Bs[((size_t)kb * 128 + nf * 16 + lr) * 8];
      acc[0][nf] = mfma16(a0, b, acc[0][nf]);
      acc[1][nf] = mfma16(a1, b, acc[1][nf]);
    }
  }
  __syncthreads();
  u16* os = sh;
#pragma unroll
  for (int nf = 0; nf < 8; ++nf) {
    const int d = nf * 16 + lr;
#pragma unroll
    for (int mf = 0; mf < 2; ++mf) {
      const int mb = w * 32 + mf * 16 + lg * 4;
      const u32 p0 = (u32)f2bf(acc[mf][nf][0]) | ((u32)f2bf(acc[mf][nf][1]) << 16);
      const u32 p1 = (u32)f2bf(acc[mf][nf][2]) | ((u32)f2bf(acc[mf][nf][3]) << 16);
      *(u32*)&os[d * 136 + mb] = p0;
      *(u32*)&os[d * 136 + mb + 2] = p1;
    }
  }
  __syncthreads();
  const int b = m0g >> 11, mt0 = (m0g & 2047) >> 6;
#pragma unroll
  for (int i = 0; i < 8; ++i) {
    const int s = i * 256 + t;
    const int kt = s >> 10, kb = (s >> 7) & 7, d = s & 127;
    const uint4 v = *(const uint4*)&os[d * 136 + kt * 64 + kb * 8];
    *(uint4*)&suppT_sw[((size_t)((b * 32 + mt0 + kt) * 8 + kb)) * 1024 + (size_t)d * 8] = v;
  }
}

// ---------------- K_gcn ------------------------------------------------------
__global__ __launch_bounds__(256) void k_gcn(const u16* __restrict__ adj_sw,
                                             const u16* __restrict__ suppT_sw,
                                             const float* __restrict__ bias,
                                             float* __restrict__ h,
                                             float* __restrict__ psum,
                                             float* __restrict__ psq) {
  const int nt = blockIdx.x;
  const int b = blockIdx.y;
  const int n0 = nt * 64;
  const int t = threadIdx.x;
  const int w = t >> 6, l = t & 63;
  const int wm = w >> 1, wn = w & 1;
  const int lg = l >> 4, lr = l & 15;
  __shared__ __align__(16) u16 As[2][4096];
  __shared__ __align__(16) u16 Bs[2][8192];
  __shared__ float redS[2][128], redQ[2][128];

  f32x4 acc[2][4];
#pragma unroll
  for (int mf = 0; mf < 2; ++mf)
#pragma unroll
    for (int nf = 0; nf < 4; ++nf) {
      acc[mf][nf][0] = 0.f; acc[mf][nf][1] = 0.f;
      acc[mf][nf][2] = 0.f; acc[mf][nf][3] = 0.f;
    }

#define GCN_STAGE(buf, kt)                                                       \
  {                                                                              \
    _Pragma("unroll") for (int i = 0; i < 2; ++i) {                              \
      const int s0 = i * 256 + w * 64;                                           \
      gload16(adj_sw + ((size_t)(nt * 32 + (kt))) * 4096 + (size_t)(s0 + l) * 8, \
              &As[buf][s0 * 8]);                                                 \
    }                                                                            \
    _Pragma("unroll") for (int i = 0; i < 4; ++i) {                              \
      const int s0 = i * 256 + w * 64;                                           \
      gload16(suppT_sw + ((size_t)(b * 32 + (kt))) * 8192 + (size_t)(s0 + l) * 8,\
              &Bs[buf][s0 * 8]);                                                 \
    }                                                                            \
  }

  GCN_STAGE(0, 0);
  __syncthreads();
  for (int kt = 0; kt < 32; ++kt) {
    const int cur = kt & 1;
    if (kt + 1 < 32) GCN_STAGE(cur ^ 1, kt + 1);
#pragma unroll
    for (int kb = 0; kb < 2; ++kb) {
      const int ko = kb * 4 + lg;
      const bf16x8 a0 = *(const bf16x8*)&As[cur][(ko * 64 + wm * 32 + lr) * 8];
      const bf16x8 a1 = *(const bf16x8*)&As[cur][(ko * 64 + wm * 32 + 16 + lr) * 8];
      const bf16x8 b0 = *(const bf16x8*)&Bs[cur][(ko * 128 + wn * 64 + lr) * 8];
      const bf16x8 b1 = *(const bf16x8*)&Bs[cur][(ko * 128 + wn * 64 + 16 + lr) * 8];
      const bf16x8 b2 = *(const bf16x8*)&Bs[cur][(ko * 128 + wn * 64 + 32 + lr) * 8];
      const bf16x8 b3 = *(const bf16x8*)&Bs[cur][(ko * 128 + wn * 64 + 48 + lr) * 8];
      acc[0][0] = mfma16(a0, b0, acc[0][0]);
      acc[0][1] = mfma16(a0, b1, acc[0][1]);
      acc[0][2] = mfma16(a0, b2, acc[0][2]);
      acc[0][3] = mfma16(a0, b3, acc[0][3]);
      acc[1][0] = mfma16(a1, b0, acc[1][0]);
      acc[1][1] = mfma16(a1, b1, acc[1][1]);
      acc[1][2] = mfma16(a1, b2, acc[1][2]);
      acc[1][3] = mfma16(a1, b3, acc[1][3]);
    }
    __syncthreads();
  }
#undef GCN_STAGE
#pragma unroll
  for (int nf = 0; nf < 4; ++nf) {
    const int d = wn * 64 + nf * 16 + lr;
    const float bv = bias[d];
    float s = 0.f, q = 0.f;
#pragma unroll
    for (int mf = 0; mf < 2; ++mf) {
#pragma unroll
      for (int r = 0; r < 4; ++r) {
        const float v = acc[mf][nf][r] + bv;
        const int row = n0 + wm * 32 + mf * 16 + lg * 4 + r;
        h[((size_t)(b * NN + row)) * NH + d] = v;
        s += v;
        q = fmaf(v, v, q);
      }
    }
    s += __shfl_xor(s, 16);
    s += __shfl_xor(s, 32);
    q += __shfl_xor(q, 16);
    q += __shfl_xor(q, 32);
    if (lg == 0) {
      redS[wm][d] = s;
      redQ[wm][d] = q;
    }
  }
  __syncthreads();
  if (t < 128) {
    const int blk = b * 32 + nt;
    psum[blk * 128 + t] = redS[0][t] + redS[1][t];
    psq[blk * 128 + t] = redQ[0][t] + redQ[1][t];
  }
}

// ---------------- BN finalize ------------------------------------------------
__global__ __launch_bounds__(1024) void k_bnstat2(const float* __restrict__ psum,
                                                  const float* __restrict__ psq,
                                                  const float* __restrict__ gamma,
                                                  const float* __restrict__ beta,
                                                  float* __restrict__ scale,
                                                  float* __restrict__ shift) {
  const int t = threadIdx.x;
  const int d = t & 127;
  const int g = t >> 7;
  float s = 0.f, q = 0.f;
  for (int i = g; i < 512; i += 8) {
    s += psum[i * 128 + d];
    q += psq[i * 128 + d];
  }
  __shared__ float ls[8][128], lq[8][128];
  ls[g][d] = s;
  lq[g][d] = q;
  __syncthreads();
  if (t < 128) {
    s = 0.f;
    q = 0.f;
#pragma unroll
    for (int i = 0; i < 8; ++i) {
      s += ls[i][t];
      q += lq[i][t];
    }
    const float inv = 1.f / (float)(NB * NN);
    const float mean = s * inv;
    const float var = q * inv - mean * mean;
    const float sc = gamma[t] * rsqrtf(var + 1e-5f);
    scale[t] = sc;
    shift[t] = beta[t] - mean * sc;
  }
}

// ---------------- K_hp -------------------------------------------------------
__global__ __launch_bounds__(256) void k_hp(const float* __restrict__ h,
                                            const float* __restrict__ scale,
                                            const float* __restrict__ shift,
                                            const float* __restrict__ gWT,
                                            u16* __restrict__ hp_sw) {
  const int row0 = blockIdx.x * 64;
  __shared__ float hs[64][132];
  __shared__ __align__(16) u16 hos[64][72];
  const int t = threadIdx.x;
#pragma unroll
  for (int k = 0; k < 8; ++k) {
    const int s = t + k * 256;
    const int row = s >> 5, c4 = (s & 31) * 4;
    const float4 v = *(const float4*)&h[(size_t)(row0 + row) * NH + c4];
    const float4 sc = *(const float4*)&scale[c4];
    const float4 sh = *(const float4*)&shift[c4];
    hs[row][c4 + 0] = fmaxf(fmaf(v.x, sc.x, sh.x), 0.f);
    hs[row][c4 + 1] = fmaxf(fmaf(v.y, sc.y, sh.y), 0.f);
    hs[row][c4 + 2] = fmaxf(fmaf(v.z, sc.z, sh.z), 0.f);
    hs[row][c4 + 3] = fmaxf(fmaf(v.w, sc.w, sh.w), 0.f);
  }
  __syncthreads();
  const int c = t & 63, q = t >> 6;
  float acc[16];
#pragma unroll
  for (int r = 0; r < 16; ++r) acc[r] = 0.f;
  for (int c4 = 0; c4 < 32; ++c4) {
    const float4 wv = *(const float4*)&gWT[c * 128 + c4 * 4];
#pragma unroll
    for (int r = 0; r < 16; ++r) {
      const float4 hv = *(const float4*)&hs[q * 16 + r][c4 * 4];
      acc[r] = fmaf(hv.x, wv.x, fmaf(hv.y, wv.y, fmaf(hv.z, wv.z, fmaf(hv.w, wv.w, acc[r]))));
    }
  }
#pragma unroll
  for (int r = 0; r < 16; ++r) hos[q * 16 + r][c] = f2bf(acc[r]);
  __syncthreads();
  const size_t tbase = (size_t)blockIdx.x * 4096;
#pragma unroll
  for (int k = 0; k < 2; ++k) {
    const int s = t + k * 256;
    const int kb = s >> 6, r6 = s & 63;
    const uint2 lo = *(const uint2*)&hos[r6][kb * 8];
    const uint2 hi = *(const uint2*)&hos[r6][kb * 8 + 4];
    uint4 o;
    o.x = lo.x; o.y = lo.y; o.z = hi.x; o.w = hi.y;
    *(uint4*)&hp_sw[tbase + kb * 512 + r6 * 8] = o;
  }
}

// ---------------- K_attnA: partial D over m-quarter --------------------------
// grid (512, 4): bx = b*32+nt, by = quarter. Each block: 8 mt tiles of 64 m.
__global__ __launch_bounds__(256) void k_attnA(const u16* __restrict__ hp_sw,
                                               float* __restrict__ Dpart) {
  const int bx = blockIdx.x, qtr = blockIdx.y;
  const int b = bx >> 5, nt = bx & 31;
  const int t = threadIdx.x, w = t >> 6, l = t & 63;
  const int lg = l >> 4, lr = l & 15;
  __shared__ __align__(16) u16 Cs[2][4096];
  const u16* rbase = hp_sw + (size_t)(b * 32 + nt) * 4096;
  const int qrow = (w << 4) + lr;
  const bf16x8 bq0 = *(const bf16x8*)&rbase[(lg * 64 + qrow) * 8];
  const bf16x8 bq1 = *(const bf16x8*)&rbase[((lg + 4) * 64 + qrow) * 8];
  const u16* cb = hp_sw + (size_t)(b * 32 + qtr * 8) * 4096;
#pragma unroll
  for (int i = 0; i < 2; ++i) gload16(cb + (size_t)(i * 256 + t) * 8, &Cs[0][(i * 256 + t) * 8]);
  __syncthreads();
  float S = 0.f;
  for (int mt = 0; mt < 8; ++mt) {
    const int cur = mt & 1;
    if (mt + 1 < 8) {
#pragma unroll
      for (int i = 0; i < 2; ++i)
        gload16(cb + (size_t)(mt + 1) * 4096 + (size_t)(i * 256 + t) * 8,
                &Cs[cur ^ 1][(i * 256 + t) * 8]);
    }
#pragma unroll
    for (int mf = 0; mf < 4; ++mf) {
      const bf16x8 a0 = *(const bf16x8*)&Cs[cur][(lg * 64 + mf * 16 + lr) * 8];
      const bf16x8 a1 = *(const bf16x8*)&Cs[cur][((lg + 4) * 64 + mf * 16 + lr) * 8];
      f32x4 z;
      z[0] = 0.f; z[1] = 0.f; z[2] = 0.f; z[3] = 0.f;
      z = mfma16(a0, bq0, z);
      z = mfma16(a1, bq1, z);
      S += explr(z[0]) + explr(z[1]) + explr(z[2]) + explr(z[3]);
    }
    __syncthreads();
  }
  S += __shfl_xor(S, 16);
  S += __shfl_xor(S, 32);
  if (l < 16) Dpart[qtr * 32768 + b * NN + nt * 64 + qrow] = S;
}

// ---------------- K_dmerge: iD = 1/(D0+D1+D2+D3) -----------------------------
__global__ __launch_bounds__(256) void k_dmerge(const float* __restrict__ Dpart,
                                                float* __restrict__ iDbuf) {
  const int i = (blockIdx.x * 256 + threadIdx.x) * 4;
  const float4 a = *(const float4*)&Dpart[i];
  const float4 bq = *(const float4*)&Dpart[32768 + i];
  const float4 c = *(const float4*)&Dpart[65536 + i];
  const float4 d = *(const float4*)&Dpart[98304 + i];
  float4 o;
  o.x = 1.f / (a.x + bq.x + c.x + d.x);
  o.y = 1.f / (a.y + bq.y + c.y + d.y);
  o.z = 1.f / (a.z + bq.z + c.z + d.z);
  o.w = 1.f / (a.w + bq.w + c.w + d.w);
  *(float4*)&iDbuf[i] = o;
}

// ---------------- K_attnB: partial S over m-quarter --------------------------
__global__ __launch_bounds__(256) void k_attnB(const u16* __restrict__ hp_sw,
                                               const float* __restrict__ iDbuf,
                                               float* __restrict__ Spart) {
  const int bx = blockIdx.x, qtr = blockIdx.y;
  const int b = bx >> 5, nt = bx & 31;
  const int t = threadIdx.x, w = t >> 6, l = t & 63;
  const int lg = l >> 4, lr = l & 15;
  __shared__ __align__(16) u16 Cs[2][4096];
  const u16* rbase = hp_sw + (size_t)(b * 32 + nt) * 4096;
  const int qrow = (w << 4) + lr;
  const bf16x8 bq0 = *(const bf16x8*)&rbase[(lg * 64 + qrow) * 8];
  const bf16x8 bq1 = *(const bf16x8*)&rbase[((lg + 4) * 64 + qrow) * 8];
  const u16* cb = hp_sw + (size_t)(b * 32 + qtr * 8) * 4096;
  const float* dbase = iDbuf + b * NN + qtr * 512;
#pragma unroll
  for (int i = 0; i < 2; ++i) gload16(cb + (size_t)(i * 256 + t) * 8, &Cs[0][(i * 256 + t) * 8]);
  __syncthreads();
  float S = 0.f;
  for (int mt = 0; mt < 8; ++mt) {
    const int cur = mt & 1;
    if (mt + 1 < 8) {
#pragma unroll
      for (int i = 0; i < 2; ++i)
        gload16(cb + (size_t)(mt + 1) * 4096 + (size_t)(i * 256 + t) * 8,
                &Cs[cur ^ 1][(i * 256 + t) * 8]);
    }
#pragma unroll
    for (int mf = 0; mf < 4; ++mf) {
      const bf16x8 a0 = *(const bf16x8*)&Cs[cur][(lg * 64 + mf * 16 + lr) * 8];
      const bf16x8 a1 = *(const bf16x8*)&Cs[cur][((lg + 4) * 64 + mf * 16 + lr) * 8];
      f32x4 z;
      z[0] = 0.f; z[1] = 0.f; z[2] = 0.f; z[3] = 0.f;
      z = mfma16(a0, bq0, z);
      z = mfma16(a1, bq1, z);
      const float4 dv = *(const float4*)&dbase[mt * 64 + mf * 16 + lg * 4];
      S = fmaf(explr(z[0]), dv.x, S);
      S = fmaf(explr(z[1]), dv.y, S);
      S = fmaf(explr(z[2]), dv.z, S);
      S = fmaf(explr(z[3]), dv.w, S);
    }
    __syncthreads();
  }
  S += __shfl_xor(S, 16);
  S += __shfl_xor(S, 32);
  if (l < 16) Spart[qtr * 32768 + b * NN + nt * 64 + qrow] = S;
}

// ---------------- K_scale: out = hp * (S0+S1+S2+S3) --------------------------
__global__ __launch_bounds__(256) void k_scale(const u16* __restrict__ hp_sw,
                                               const float* __restrict__ Spart,
                                               float* __restrict__ out) {
  const int bx = blockIdx.x;
  const int b = bx >> 5, nt = bx & 31;
  const int t = threadIdx.x;
  __shared__ float Sv[64];
  if (t < 64) {
    const int n = b * NN + nt * 64 + t;
    Sv[t] = Spart[n] + Spart[32768 + n] + Spart[65536 + n] + Spart[98304 + n];
  }
  __syncthreads();
  const u16* rbase = hp_sw + (size_t)(b * 32 + nt) * 4096;
  const int row = t >> 2;
  const float sc = Sv[row];
  const size_t R = (size_t)b * NN + nt * 64 + row;
#pragma unroll
  for (int hh = 0; hh < 2; ++hh) {
    const int kb = (t & 3) * 2 + hh;
    const u16* src = &rbase[(kb * 64 + row) * 8];
    float4 o0, o1;
    o0.x = bf2f(src[0]) * sc;
    o0.y = bf2f(src[1]) * sc;
    o0.z = bf2f(src[2]) * sc;
    o0.w = bf2f(src[3]) * sc;
    o1.x = bf2f(src[4]) * sc;
    o1.y = bf2f(src[5]) * sc;
    o1.z = bf2f(src[6]) * sc;
    o1.w = bf2f(src[7]) * sc;
    *(float4*)&out[R * NO + kb * 8] = o0;
    *(float4*)&out[R * NO + kb * 8 + 4] = o1;
  }
}

extern "C" void kernel_launch(void* const* d_in, const int* in_sizes, int n_in,
                              void* d_out, int out_size, void* d_ws, size_t ws_size,
                              hipStream_t stream) {
  const float* x = (const float*)d_in[0];
  // d_in[1] = adj (unused)
  const float* adj_gcn = (const float*)d_in[2];
  const float* gcn_w = (const float*)d_in[3];
  const float* gcn_b = (const float*)d_in[4];
  const float* gamma = (const float*)d_in[5];
  const float* beta = (const float*)d_in[6];
  const float* gat_w = (const float*)d_in[7];
  float* out = (float*)d_out;
  float* ws = (float*)d_ws;

  // workspace layout (float units), peak ~39.6MB (ws is 256MB):
  u16* adj_sw = (u16*)ws;                  // [0, 2M)
  u16* suppT_sw = (u16*)(ws + 2097152);    // [2M, 4M)
  float* hbuf = ws + 4194304;              // [4M, 8M)
  u16* x_sw = (u16*)(ws + 4194304);        // aliases hbuf lower half (dead first)
  u16* hp_sw = (u16*)(ws + 8388608);       // [8M, 9M)
  float* iDbuf = ws + 9437184;             // 32768
  float* psum = iDbuf + 32768;             // 65536
  float* psq = psum + 65536;               // 65536
  float* scale = psq + 65536;              // 128
  float* shift = scale + 128;              // 128
  float* gWT = shift + 128;                // 8192
  u16* Wsw = (u16*)(gWT + 8192);           // 16384 u16 (8192 f)
  float* Dpart = ws + 9617664;             // 131072
  float* Spart = Dpart + 131072;           // 131072

  k_prep<<<dim3(1289), dim3(256), 0, stream>>>(x, adj_gcn, gcn_w, gat_w, x_sw, adj_sw, gWT, Wsw);
  k_support<<<dim3(256), dim3(256), 0, stream>>>(x_sw, Wsw, suppT_sw);
  k_gcn<<<dim3(32, 16), dim3(256), 0, stream>>>(adj_sw, suppT_sw, gcn_b, hbuf, psum, psq);
  k_bnstat2<<<dim3(1), dim3(1024), 0, stream>>>(psum, psq, gamma, beta, scale, shift);
  k_hp<<<dim3(512), dim3(256), 0, stream>>>(hbuf, scale, shift, gWT, hp_sw);
  k_attnA<<<dim3(512, 4), dim3(256), 0, stream>>>(hp_sw, Dpart);
  k_dmerge<<<dim3(32), dim3(256), 0, stream>>>(Dpart, iDbuf);
  k_attnB<<<dim3(512, 4), dim3(256), 0, stream>>>(hp_sw, iDbuf, Spart);
  k_scale<<<dim3(512), dim3(256), 0, stream>>>(hp_sw, Spart, out);
}

// Round 9
// 115.944 us; speedup vs baseline: 2.7873x; 1.1299x over previous
//
#include <hip/hip_runtime.h>
#include <math.h>

#define NB 16
#define NN 2048
#define NF 128
#define NH 128
#define NO 64

typedef short bf16x8 __attribute__((ext_vector_type(8)));
typedef float f32x4 __attribute__((ext_vector_type(4)));
typedef unsigned short u16;
typedef unsigned int u32;

#define LOG2E 1.4426950408889634f
#define EXPSHIFT 43.28085122666891f  // 30 * log2(e)

__device__ __forceinline__ u16 f2bf(float f) {
  u32 u = __builtin_bit_cast(u32, f);
  return (u16)((u + 0x7fffu + ((u >> 16) & 1u)) >> 16);
}
__device__ __forceinline__ float bf2f(u16 h) {
  u32 u = ((u32)h) << 16;
  return __builtin_bit_cast(float, u);
}

__device__ __forceinline__ void gload16(const void* g, void* l) {
  __builtin_amdgcn_global_load_lds((const __attribute__((address_space(1))) void*)g,
                                   (__attribute__((address_space(3))) void*)l, 16, 0, 0);
}
__device__ __forceinline__ f32x4 mfma16(bf16x8 a, bf16x8 b, f32x4 c) {
  return __builtin_amdgcn_mfma_f32_16x16x32_bf16(a, b, c, 0, 0, 0);
}
// exp(lrelu(z) - 30): max, mul, fma, v_exp
__device__ __forceinline__ float explr(float z) {
  return __builtin_amdgcn_exp2f(fmaf(fmaxf(z, 0.2f * z), LOG2E, -EXPSHIFT));
}

// ---------------- K_prep -----------------------------------------------------
// bid 0      : Wg_sw = gat_w bf16 in [kblk 16][col 64][8] image
// bid 1..8   : Wsw  = gcn_w bf16 in [kblk 16][d 128][8] image
// bid 9..264 : x_sw = x bf16 in [rowblk 256][kblk 16][row 128][8] image
// bid 265..  : adj_sw = adj bf16 in [ntile 32][ktile 32][kblk 8][row 64][8]
__global__ __launch_bounds__(256) void k_prep(const float* __restrict__ x,
                                              const float* __restrict__ adj,
                                              const float* __restrict__ gcn_w,
                                              const float* __restrict__ gat_w,
                                              u16* __restrict__ x_sw,
                                              u16* __restrict__ adj_sw,
                                              u16* __restrict__ Wg_sw,
                                              u16* __restrict__ Wsw) {
  __shared__ u16 ts[128 * 136];
  const int t = threadIdx.x;
  const int bid = blockIdx.x;
  if (bid == 0) {
#pragma unroll
    for (int it = 0; it < 4; ++it) {
      const int s = t + it * 256;  // [kb 16][col 64]
      const int kb = s >> 6, col = s & 63;
      u16 tmp[8];
#pragma unroll
      for (int j = 0; j < 8; ++j) tmp[j] = f2bf(gat_w[(kb * 8 + j) * 64 + col]);
      uint4 o;
      o.x = (u32)tmp[0] | ((u32)tmp[1] << 16);
      o.y = (u32)tmp[2] | ((u32)tmp[3] << 16);
      o.z = (u32)tmp[4] | ((u32)tmp[5] << 16);
      o.w = (u32)tmp[6] | ((u32)tmp[7] << 16);
      *(uint4*)&Wg_sw[(size_t)s * 8] = o;
    }
  } else if (bid < 9) {
    const int s = (bid - 1) * 256 + t;
    const int kb = s >> 7, d = s & 127;
    u16 tmp[8];
#pragma unroll
    for (int j = 0; j < 8; ++j) tmp[j] = f2bf(gcn_w[(kb * 8 + j) * 128 + d]);
    uint4 o;
    o.x = (u32)tmp[0] | ((u32)tmp[1] << 16);
    o.y = (u32)tmp[2] | ((u32)tmp[3] << 16);
    o.z = (u32)tmp[4] | ((u32)tmp[5] << 16);
    o.w = (u32)tmp[6] | ((u32)tmp[7] << 16);
    *(uint4*)&Wsw[(size_t)s * 8] = o;
  } else if (bid < 265) {
    const int blk = bid - 9;
    const size_t r0 = (size_t)blk * 128;
#pragma unroll
    for (int k = 0; k < 16; ++k) {
      const int s = t + k * 256;
      const int row = s >> 5, c4 = (s & 31) * 4;
      const float4 f = *(const float4*)&x[(r0 + row) * 128 + c4];
      uint2 pk;
      pk.x = (u32)f2bf(f.x) | ((u32)f2bf(f.y) << 16);
      pk.y = (u32)f2bf(f.z) | ((u32)f2bf(f.w) << 16);
      *(uint2*)&ts[row * 136 + c4] = pk;
    }
    __syncthreads();
#pragma unroll
    for (int k = 0; k < 8; ++k) {
      const int s = t + k * 256;
      const int kb = s >> 7, row = s & 127;
      const uint4 v = *(const uint4*)&ts[row * 136 + kb * 8];
      *(uint4*)&x_sw[(size_t)blk * 16384 + (size_t)s * 8] = v;
    }
  } else {
    const int tile = bid - 265;
    const int n0 = (tile >> 5) * 64, m0 = (tile & 31) * 64;
#pragma unroll
    for (int k = 0; k < 4; ++k) {
      const int s = t + k * 256;
      const int row = s >> 4, c4 = (s & 15) * 4;
      const float4 f = *(const float4*)&adj[(size_t)(n0 + row) * 2048 + m0 + c4];
      uint2 pk;
      pk.x = (u32)f2bf(f.x) | ((u32)f2bf(f.y) << 16);
      pk.y = (u32)f2bf(f.z) | ((u32)f2bf(f.w) << 16);
      *(uint2*)&ts[row * 136 + c4] = pk;
    }
    __syncthreads();
#pragma unroll
    for (int k = 0; k < 2; ++k) {
      const int s = t + k * 256;
      const int kb = s >> 6, row = s & 63;
      const uint4 v = *(const uint4*)&ts[row * 136 + kb * 8];
      *(uint4*)&adj_sw[(size_t)tile * 4096 + (size_t)s * 8] = v;
    }
  }
}

// ---------------- K_support --------------------------------------------------
__global__ __launch_bounds__(256) void k_support(const u16* __restrict__ x_sw,
                                                 const u16* __restrict__ Wsw,
                                                 u16* __restrict__ suppT_sw) {
  const int m0g = blockIdx.x * 128;
  const int t = threadIdx.x, w = t >> 6, l = t & 63;
  const int lg = l >> 4, lr = l & 15;
  __shared__ __align__(16) u16 sh[32768];
  u16* As = sh;
  u16* Bs = sh + 16384;
#pragma unroll
  for (int i = 0; i < 8; ++i) {
    const int s0 = i * 256 + w * 64;
    gload16(x_sw + (size_t)blockIdx.x * 16384 + (size_t)(s0 + l) * 8, &As[(size_t)s0 * 8]);
  }
#pragma unroll
  for (int i = 0; i < 8; ++i) {
    const int s0 = i * 256 + w * 64;
    gload16(Wsw + (size_t)(s0 + l) * 8, &Bs[(size_t)s0 * 8]);
  }
  __syncthreads();
  f32x4 acc[2][8];
#pragma unroll
  for (int mf = 0; mf < 2; ++mf)
#pragma unroll
    for (int nf = 0; nf < 8; ++nf) {
      acc[mf][nf][0] = 0.f; acc[mf][nf][1] = 0.f;
      acc[mf][nf][2] = 0.f; acc[mf][nf][3] = 0.f;
    }
#pragma unroll
  for (int ks = 0; ks < 4; ++ks) {
    const int kb = ks * 4 + lg;
    const bf16x8 a0 = *(const bf16x8*)&As[((size_t)kb * 128 + w * 32 + lr) * 8];
    const bf16x8 a1 = *(const bf16x8*)&As[((size_t)kb * 128 + w * 32 + 16 + lr) * 8];
#pragma unroll
    for (int nf = 0; nf < 8; ++nf) {
      const bf16x8 b = *(const bf16x8*)&Bs[((size_t)kb * 128 + nf * 16 + lr) * 8];
      acc[0][nf] = mfma16(a0, b, acc[0][nf]);
      acc[1][nf] = mfma16(a1, b, acc[1][nf]);
    }
  }
  __syncthreads();
  u16* os = sh;
#pragma unroll
  for (int nf = 0; nf < 8; ++nf) {
    const int d = nf * 16 + lr;
#pragma unroll
    for (int mf = 0; mf < 2; ++mf) {
      const int mb = w * 32 + mf * 16 + lg * 4;
      const u32 p0 = (u32)f2bf(acc[mf][nf][0]) | ((u32)f2bf(acc[mf][nf][1]) << 16);
      const u32 p1 = (u32)f2bf(acc[mf][nf][2]) | ((u32)f2bf(acc[mf][nf][3]) << 16);
      *(u32*)&os[d * 136 + mb] = p0;
      *(u32*)&os[d * 136 + mb + 2] = p1;
    }
  }
  __syncthreads();
  const int b = m0g >> 11, mt0 = (m0g & 2047) >> 6;
#pragma unroll
  for (int i = 0; i < 8; ++i) {
    const int s = i * 256 + t;
    const int kt = s >> 10, kb = (s >> 7) & 7, d = s & 127;
    const uint4 v = *(const uint4*)&os[d * 136 + kt * 64 + kb * 8];
    *(uint4*)&suppT_sw[((size_t)((b * 32 + mt0 + kt) * 8 + kb)) * 1024 + (size_t)d * 8] = v;
  }
}

// ---------------- K_gcn: 64x128 tile, BK=64, 8 waves (512 thr) ---------------
__global__ __launch_bounds__(512) void k_gcn(const u16* __restrict__ adj_sw,
                                             const u16* __restrict__ suppT_sw,
                                             const float* __restrict__ bias,
                                             float* __restrict__ h,
                                             float* __restrict__ psum,
                                             float* __restrict__ psq) {
  const int nt = blockIdx.x;
  const int b = blockIdx.y;
  const int n0 = nt * 64;
  const int t = threadIdx.x;
  const int w = t >> 6, l = t & 63;
  const int wm = w >> 1, wn = w & 1;  // wm 0..3 (16-row group), wn 0..1 (64-col)
  const int lg = l >> 4, lr = l & 15;
  __shared__ __align__(16) u16 As[2][4096];  // [8 kblk][64 row][8]
  __shared__ __align__(16) u16 Bs[2][8192];  // [8 kblk][128 d][8]
  __shared__ float redS[4][128], redQ[4][128];

  f32x4 acc[4];
#pragma unroll
  for (int nf = 0; nf < 4; ++nf) {
    acc[nf][0] = 0.f; acc[nf][1] = 0.f;
    acc[nf][2] = 0.f; acc[nf][3] = 0.f;
  }

#define GCN_STAGE(buf, kt)                                                        \
  {                                                                               \
    gload16(adj_sw + ((size_t)(nt * 32 + (kt))) * 4096 + (size_t)t * 8,           \
            &As[buf][t * 8]);                                                     \
    _Pragma("unroll") for (int i = 0; i < 2; ++i) {                               \
      const int s = i * 512 + t;                                                  \
      gload16(suppT_sw + ((size_t)(b * 32 + (kt))) * 8192 + (size_t)s * 8,        \
              &Bs[buf][s * 8]);                                                   \
    }                                                                             \
  }

  GCN_STAGE(0, 0);
  __syncthreads();
  for (int kt = 0; kt < 32; ++kt) {
    const int cur = kt & 1;
    if (kt + 1 < 32) GCN_STAGE(cur ^ 1, kt + 1);
#pragma unroll
    for (int kb = 0; kb < 2; ++kb) {
      const int ko = kb * 4 + lg;
      const bf16x8 a0 = *(const bf16x8*)&As[cur][(ko * 64 + wm * 16 + lr) * 8];
      const bf16x8 b0 = *(const bf16x8*)&Bs[cur][(ko * 128 + wn * 64 + lr) * 8];
      const bf16x8 b1 = *(const bf16x8*)&Bs[cur][(ko * 128 + wn * 64 + 16 + lr) * 8];
      const bf16x8 b2 = *(const bf16x8*)&Bs[cur][(ko * 128 + wn * 64 + 32 + lr) * 8];
      const bf16x8 b3 = *(const bf16x8*)&Bs[cur][(ko * 128 + wn * 64 + 48 + lr) * 8];
      acc[0] = mfma16(a0, b0, acc[0]);
      acc[1] = mfma16(a0, b1, acc[1]);
      acc[2] = mfma16(a0, b2, acc[2]);
      acc[3] = mfma16(a0, b3, acc[3]);
    }
    __syncthreads();
  }
#undef GCN_STAGE
#pragma unroll
  for (int nf = 0; nf < 4; ++nf) {
    const int d = wn * 64 + nf * 16 + lr;
    const float bv = bias[d];
    float s = 0.f, q = 0.f;
#pragma unroll
    for (int r = 0; r < 4; ++r) {
      const float v = acc[nf][r] + bv;
      const int row = n0 + wm * 16 + lg * 4 + r;
      h[((size_t)(b * NN + row)) * NH + d] = v;
      s += v;
      q = fmaf(v, v, q);
    }
    s += __shfl_xor(s, 16);
    s += __shfl_xor(s, 32);
    q += __shfl_xor(q, 16);
    q += __shfl_xor(q, 32);
    if (lg == 0) {
      redS[wm][d] = s;
      redQ[wm][d] = q;
    }
  }
  __syncthreads();
  if (t < 128) {
    const int blk = b * 32 + nt;
    psum[blk * 128 + t] = redS[0][t] + redS[1][t] + redS[2][t] + redS[3][t];
    psq[blk * 128 + t] = redQ[0][t] + redQ[1][t] + redQ[2][t] + redQ[3][t];
  }
}

// ---------------- BN finalize ------------------------------------------------
__global__ __launch_bounds__(1024) void k_bnstat2(const float* __restrict__ psum,
                                                  const float* __restrict__ psq,
                                                  const float* __restrict__ gamma,
                                                  const float* __restrict__ beta,
                                                  float* __restrict__ scale,
                                                  float* __restrict__ shift) {
  const int t = threadIdx.x;
  const int d = t & 127;
  const int g = t >> 7;
  float s = 0.f, q = 0.f;
  for (int i = g; i < 512; i += 8) {
    s += psum[i * 128 + d];
    q += psq[i * 128 + d];
  }
  __shared__ float ls[8][128], lq[8][128];
  ls[g][d] = s;
  lq[g][d] = q;
  __syncthreads();
  if (t < 128) {
    s = 0.f;
    q = 0.f;
#pragma unroll
    for (int i = 0; i < 8; ++i) {
      s += ls[i][t];
      q += lq[i][t];
    }
    const float inv = 1.f / (float)(NB * NN);
    const float mean = s * inv;
    const float var = q * inv - mean * mean;
    const float sc = gamma[t] * rsqrtf(var + 1e-5f);
    scale[t] = sc;
    shift[t] = beta[t] - mean * sc;
  }
}

// ---------------- K_hp: MFMA version -----------------------------------------
// him: bf16 [64 row][128 k] with XOR swizzle byte ^= (row&7)<<4 (bank-safe both ways)
__global__ __launch_bounds__(256) void k_hp(const float* __restrict__ h,
                                            const float* __restrict__ scale,
                                            const float* __restrict__ shift,
                                            const u16* __restrict__ Wg_sw,
                                            u16* __restrict__ hp_sw) {
  const int row0 = blockIdx.x * 64;
  const int t = threadIdx.x, w = t >> 6, l = t & 63;
  const int lg = l >> 4, lr = l & 15;
  __shared__ __align__(16) u16 him[8192];   // 16KB swizzled h-bf16 image
  __shared__ __align__(16) u16 Wg[8192];    // 16KB [kb 16][col 64][8]
  __shared__ __align__(16) u16 hos[64][72];
  __shared__ float scs[128], shs[128];
  // stage Wg (linear) early
#pragma unroll
  for (int i = 0; i < 4; ++i) {
    const int s0 = i * 256 + w * 64;
    gload16(Wg_sw + (size_t)(s0 + l) * 8, &Wg[(size_t)s0 * 8]);
  }
  if (t < 128) {
    scs[t] = scale[t];
    shs[t] = shift[t];
  }
  __syncthreads();
  // load h (coalesced), BN+relu, pack, swizzled ds_write
#pragma unroll
  for (int k = 0; k < 4; ++k) {
    const int s = t + k * 256;  // [row 64][kb 16]
    const int row = s >> 4, kb = s & 15;
    const float4 v0 = *(const float4*)&h[(size_t)(row0 + row) * NH + kb * 8];
    const float4 v1 = *(const float4*)&h[(size_t)(row0 + row) * NH + kb * 8 + 4];
    u16 p[8];
    p[0] = f2bf(fmaxf(fmaf(v0.x, scs[kb * 8 + 0], shs[kb * 8 + 0]), 0.f));
    p[1] = f2bf(fmaxf(fmaf(v0.y, scs[kb * 8 + 1], shs[kb * 8 + 1]), 0.f));
    p[2] = f2bf(fmaxf(fmaf(v0.z, scs[kb * 8 + 2], shs[kb * 8 + 2]), 0.f));
    p[3] = f2bf(fmaxf(fmaf(v0.w, scs[kb * 8 + 3], shs[kb * 8 + 3]), 0.f));
    p[4] = f2bf(fmaxf(fmaf(v1.x, scs[kb * 8 + 4], shs[kb * 8 + 4]), 0.f));
    p[5] = f2bf(fmaxf(fmaf(v1.y, scs[kb * 8 + 5], shs[kb * 8 + 5]), 0.f));
    p[6] = f2bf(fmaxf(fmaf(v1.z, scs[kb * 8 + 6], shs[kb * 8 + 6]), 0.f));
    p[7] = f2bf(fmaxf(fmaf(v1.w, scs[kb * 8 + 7], shs[kb * 8 + 7]), 0.f));
    uint4 o;
    o.x = (u32)p[0] | ((u32)p[1] << 16);
    o.y = (u32)p[2] | ((u32)p[3] << 16);
    o.z = (u32)p[4] | ((u32)p[5] << 16);
    o.w = (u32)p[6] | ((u32)p[7] << 16);
    const int boff = (row * 256 + kb * 16) ^ ((row & 7) << 4);
    *(uint4*)&him[boff >> 1] = o;
  }
  __syncthreads();
  // MFMA: wave w -> rows w*16..+16, cols 0..63
  f32x4 acc[4];
#pragma unroll
  for (int nf = 0; nf < 4; ++nf) {
    acc[nf][0] = 0.f; acc[nf][1] = 0.f;
    acc[nf][2] = 0.f; acc[nf][3] = 0.f;
  }
#pragma unroll
  for (int kks = 0; kks < 4; ++kks) {
    const int ko = kks * 4 + lg;
    const int arow = w * 16 + lr;
    const int aoff = (arow * 256 + ko * 16) ^ ((arow & 7) << 4);
    const bf16x8 a = *(const bf16x8*)&him[aoff >> 1];
#pragma unroll
    for (int nf = 0; nf < 4; ++nf) {
      const bf16x8 bfr = *(const bf16x8*)&Wg[(ko * 64 + nf * 16 + lr) * 8];
      acc[nf] = mfma16(a, bfr, acc[nf]);
    }
  }
  // epilogue: hos[row][col] then linear copy to hp_sw image
#pragma unroll
  for (int nf = 0; nf < 4; ++nf) {
    const int col = nf * 16 + lr;
#pragma unroll
    for (int r = 0; r < 4; ++r) {
      hos[w * 16 + lg * 4 + r][col] = f2bf(acc[nf][r]);
    }
  }
  __syncthreads();
  const size_t tbase = (size_t)blockIdx.x * 4096;
#pragma unroll
  for (int k = 0; k < 2; ++k) {
    const int s = t + k * 256;
    const int kb = s >> 6, r6 = s & 63;
    const uint2 lo = *(const uint2*)&hos[r6][kb * 8];
    const uint2 hi = *(const uint2*)&hos[r6][kb * 8 + 4];
    uint4 o;
    o.x = lo.x; o.y = lo.y; o.z = hi.x; o.w = hi.y;
    *(uint4*)&hp_sw[tbase + kb * 512 + r6 * 8] = o;
  }
}

// ---------------- K_attnA: partial D over m-quarter --------------------------
__global__ __launch_bounds__(256) void k_attnA(const u16* __restrict__ hp_sw,
                                               float* __restrict__ Dpart) {
  const int bx = blockIdx.x, qtr = blockIdx.y;
  const int b = bx >> 5, nt = bx & 31;
  const int t = threadIdx.x, w = t >> 6, l = t & 63;
  const int lg = l >> 4, lr = l & 15;
  __shared__ __align__(16) u16 Cs[2][4096];
  const u16* rbase = hp_sw + (size_t)(b * 32 + nt) * 4096;
  const int qrow = (w << 4) + lr;
  const bf16x8 bq0 = *(const bf16x8*)&rbase[(lg * 64 + qrow) * 8];
  const bf16x8 bq1 = *(const bf16x8*)&rbase[((lg + 4) * 64 + qrow) * 8];
  const u16* cb = hp_sw + (size_t)(b * 32 + qtr * 8) * 4096;
#pragma unroll
  for (int i = 0; i < 2; ++i) gload16(cb + (size_t)(i * 256 + t) * 8, &Cs[0][(i * 256 + t) * 8]);
  __syncthreads();
  float S = 0.f;
  for (int mt = 0; mt < 8; ++mt) {
    const int cur = mt & 1;
    if (mt + 1 < 8) {
#pragma unroll
      for (int i = 0; i < 2; ++i)
        gload16(cb + (size_t)(mt + 1) * 4096 + (size_t)(i * 256 + t) * 8,
                &Cs[cur ^ 1][(i * 256 + t) * 8]);
    }
#pragma unroll
    for (int mf = 0; mf < 4; ++mf) {
      const bf16x8 a0 = *(const bf16x8*)&Cs[cur][(lg * 64 + mf * 16 + lr) * 8];
      const bf16x8 a1 = *(const bf16x8*)&Cs[cur][((lg + 4) * 64 + mf * 16 + lr) * 8];
      f32x4 z;
      z[0] = 0.f; z[1] = 0.f; z[2] = 0.f; z[3] = 0.f;
      z = mfma16(a0, bq0, z);
      z = mfma16(a1, bq1, z);
      S += explr(z[0]) + explr(z[1]) + explr(z[2]) + explr(z[3]);
    }
    __syncthreads();
  }
  S += __shfl_xor(S, 16);
  S += __shfl_xor(S, 32);
  if (l < 16) Dpart[qtr * 32768 + b * NN + nt * 64 + qrow] = S;
}

// ---------------- K_attnB: partial S (computes iD in-block) ------------------
__global__ __launch_bounds__(256) void k_attnB(const u16* __restrict__ hp_sw,
                                               const float* __restrict__ Dpart,
                                               float* __restrict__ Spart) {
  const int bx = blockIdx.x, qtr = blockIdx.y;
  const int b = bx >> 5, nt = bx & 31;
  const int t = threadIdx.x, w = t >> 6, l = t & 63;
  const int lg = l >> 4, lr = l & 15;
  __shared__ __align__(16) u16 Cs[2][4096];
  __shared__ float iDs[512];
  const u16* rbase = hp_sw + (size_t)(b * 32 + nt) * 4096;
  const int qrow = (w << 4) + lr;
  const bf16x8 bq0 = *(const bf16x8*)&rbase[(lg * 64 + qrow) * 8];
  const bf16x8 bq1 = *(const bf16x8*)&rbase[((lg + 4) * 64 + qrow) * 8];
  const u16* cb = hp_sw + (size_t)(b * 32 + qtr * 8) * 4096;
#pragma unroll
  for (int i = 0; i < 2; ++i) gload16(cb + (size_t)(i * 256 + t) * 8, &Cs[0][(i * 256 + t) * 8]);
#pragma unroll
  for (int i = 0; i < 2; ++i) {
    const int idx = t + i * 256;
    const int n = b * NN + qtr * 512 + idx;
    iDs[idx] = 1.f / (Dpart[n] + Dpart[32768 + n] + Dpart[65536 + n] + Dpart[98304 + n]);
  }
  __syncthreads();
  float S = 0.f;
  for (int mt = 0; mt < 8; ++mt) {
    const int cur = mt & 1;
    if (mt + 1 < 8) {
#pragma unroll
      for (int i = 0; i < 2; ++i)
        gload16(cb + (size_t)(mt + 1) * 4096 + (size_t)(i * 256 + t) * 8,
                &Cs[cur ^ 1][(i * 256 + t) * 8]);
    }
#pragma unroll
    for (int mf = 0; mf < 4; ++mf) {
      const bf16x8 a0 = *(const bf16x8*)&Cs[cur][(lg * 64 + mf * 16 + lr) * 8];
      const bf16x8 a1 = *(const bf16x8*)&Cs[cur][((lg + 4) * 64 + mf * 16 + lr) * 8];
      f32x4 z;
      z[0] = 0.f; z[1] = 0.f; z[2] = 0.f; z[3] = 0.f;
      z = mfma16(a0, bq0, z);
      z = mfma16(a1, bq1, z);
      const float4 dv = *(const float4*)&iDs[mt * 64 + mf * 16 + lg * 4];
      S = fmaf(explr(z[0]), dv.x, S);
      S = fmaf(explr(z[1]), dv.y, S);
      S = fmaf(explr(z[2]), dv.z, S);
      S = fmaf(explr(z[3]), dv.w, S);
    }
    __syncthreads();
  }
  S += __shfl_xor(S, 16);
  S += __shfl_xor(S, 32);
  if (l < 16) Spart[qtr * 32768 + b * NN + nt * 64 + qrow] = S;
}

// ---------------- K_scale: out = hp * (S0+S1+S2+S3) --------------------------
__global__ __launch_bounds__(256) void k_scale(const u16* __restrict__ hp_sw,
                                               const float* __restrict__ Spart,
                                               float* __restrict__ out) {
  const int bx = blockIdx.x;
  const int b = bx >> 5, nt = bx & 31;
  const int t = threadIdx.x;
  __shared__ float Sv[64];
  if (t < 64) {
    const int n = b * NN + nt * 64 + t;
    Sv[t] = Spart[n] + Spart[32768 + n] + Spart[65536 + n] + Spart[98304 + n];
  }
  __syncthreads();
  const u16* rbase = hp_sw + (size_t)(b * 32 + nt) * 4096;
  const int row = t >> 2;
  const float sc = Sv[row];
  const size_t R = (size_t)b * NN + nt * 64 + row;
#pragma unroll
  for (int hh = 0; hh < 2; ++hh) {
    const int kb = (t & 3) * 2 + hh;
    const u16* src = &rbase[(kb * 64 + row) * 8];
    float4 o0, o1;
    o0.x = bf2f(src[0]) * sc;
    o0.y = bf2f(src[1]) * sc;
    o0.z = bf2f(src[2]) * sc;
    o0.w = bf2f(src[3]) * sc;
    o1.x = bf2f(src[4]) * sc;
    o1.y = bf2f(src[5]) * sc;
    o1.z = bf2f(src[6]) * sc;
    o1.w = bf2f(src[7]) * sc;
    *(float4*)&out[R * NO + kb * 8] = o0;
    *(float4*)&out[R * NO + kb * 8 + 4] = o1;
  }
}

extern "C" void kernel_launch(void* const* d_in, const int* in_sizes, int n_in,
                              void* d_out, int out_size, void* d_ws, size_t ws_size,
                              hipStream_t stream) {
  const float* x = (const float*)d_in[0];
  // d_in[1] = adj (unused)
  const float* adj_gcn = (const float*)d_in[2];
  const float* gcn_w = (const float*)d_in[3];
  const float* gcn_b = (const float*)d_in[4];
  const float* gamma = (const float*)d_in[5];
  const float* beta = (const float*)d_in[6];
  const float* gat_w = (const float*)d_in[7];
  float* out = (float*)d_out;
  float* ws = (float*)d_ws;

  // workspace layout (float units):
  u16* adj_sw = (u16*)ws;                  // [0, 2M)
  u16* suppT_sw = (u16*)(ws + 2097152);    // [2M, 4M)
  float* hbuf = ws + 4194304;              // [4M, 8M)
  u16* x_sw = (u16*)(ws + 4194304);        // aliases hbuf lower half (dead first)
  u16* hp_sw = (u16*)(ws + 8388608);       // [8M, 9M)
  float* psum = ws + 9437184;              // 65536
  float* psq = psum + 65536;               // 65536
  float* scale = psq + 65536;              // 128
  float* shift = scale + 128;              // 128
  u16* Wg_sw = (u16*)(shift + 128);        // 8192 u16 (4096 f)
  u16* Wsw = (u16*)(shift + 128 + 4096);   // 16384 u16 (8192 f)
  float* Dpart = ws + 9617664;             // 131072
  float* Spart = Dpart + 131072;           // 131072

  k_prep<<<dim3(1289), dim3(256), 0, stream>>>(x, adj_gcn, gcn_w, gat_w, x_sw, adj_sw, Wg_sw, Wsw);
  k_support<<<dim3(256), dim3(256), 0, stream>>>(x_sw, Wsw, suppT_sw);
  k_gcn<<<dim3(32, 16), dim3(512), 0, stream>>>(adj_sw, suppT_sw, gcn_b, hbuf, psum, psq);
  k_bnstat2<<<dim3(1), dim3(1024), 0, stream>>>(psum, psq, gamma, beta, scale, shift);
  k_hp<<<dim3(512), dim3(256), 0, stream>>>(hbuf, scale, shift, Wg_sw, hp_sw);
  k_attnA<<<dim3(512, 4), dim3(256), 0, stream>>>(hp_sw, Dpart);
  k_attnB<<<dim3(512, 4), dim3(256), 0, stream>>>(hp_sw, Dpart, Spart);
  k_scale<<<dim3(512), dim3(256), 0, stream>>>(hp_sw, Spart, out);
}

// Round 10
// 113.038 us; speedup vs baseline: 2.8590x; 1.0257x over previous
//
#include <hip/hip_runtime.h>
#include <math.h>

#define NB 16
#define NN 2048
#define NF 128
#define NH 128
#define NO 64

typedef short bf16x8 __attribute__((ext_vector_type(8)));
typedef float f32x4 __attribute__((ext_vector_type(4)));
typedef unsigned short u16;
typedef unsigned int u32;

#define LOG2E 1.4426950408889634f
#define EXPSHIFT 43.28085122666891f  // 30 * log2(e)

__device__ __forceinline__ u16 f2bf(float f) {
  u32 u = __builtin_bit_cast(u32, f);
  return (u16)((u + 0x7fffu + ((u >> 16) & 1u)) >> 16);
}
__device__ __forceinline__ float bf2f(u16 h) {
  u32 u = ((u32)h) << 16;
  return __builtin_bit_cast(float, u);
}

__device__ __forceinline__ void gload16(const void* g, void* l) {
  __builtin_amdgcn_global_load_lds((const __attribute__((address_space(1))) void*)g,
                                   (__attribute__((address_space(3))) void*)l, 16, 0, 0);
}
__device__ __forceinline__ f32x4 mfma16(bf16x8 a, bf16x8 b, f32x4 c) {
  return __builtin_amdgcn_mfma_f32_16x16x32_bf16(a, b, c, 0, 0, 0);
}
// exp(lrelu(z) - 30): max, mul, fma, v_exp
__device__ __forceinline__ float explr(float z) {
  return __builtin_amdgcn_exp2f(fmaf(fmaxf(z, 0.2f * z), LOG2E, -EXPSHIFT));
}

// ---------------- K_prep (adj + weights only; x handled by k_support) --------
// bid 0   : Wg_sw = gat_w bf16 [kblk 16][col 64][8]
// bid 1..8: Wsw = gcn_w bf16 [kblk 16][d 128][8]
// bid 9.. : adj_sw = adj bf16 [ntile 32][ktile 32][kblk 8][row 64][8]
__global__ __launch_bounds__(256) void k_prep(const float* __restrict__ adj,
                                              const float* __restrict__ gcn_w,
                                              const float* __restrict__ gat_w,
                                              u16* __restrict__ adj_sw,
                                              u16* __restrict__ Wg_sw,
                                              u16* __restrict__ Wsw) {
  __shared__ u16 ts[64 * 136];
  const int t = threadIdx.x;
  const int bid = blockIdx.x;
  if (bid == 0) {
#pragma unroll
    for (int it = 0; it < 4; ++it) {
      const int s = t + it * 256;  // [kb 16][col 64]
      const int kb = s >> 6, col = s & 63;
      u16 tmp[8];
#pragma unroll
      for (int j = 0; j < 8; ++j) tmp[j] = f2bf(gat_w[(kb * 8 + j) * 64 + col]);
      uint4 o;
      o.x = (u32)tmp[0] | ((u32)tmp[1] << 16);
      o.y = (u32)tmp[2] | ((u32)tmp[3] << 16);
      o.z = (u32)tmp[4] | ((u32)tmp[5] << 16);
      o.w = (u32)tmp[6] | ((u32)tmp[7] << 16);
      *(uint4*)&Wg_sw[(size_t)s * 8] = o;
    }
  } else if (bid < 9) {
    const int s = (bid - 1) * 256 + t;  // [kb 16][d 128]
    const int kb = s >> 7, d = s & 127;
    u16 tmp[8];
#pragma unroll
    for (int j = 0; j < 8; ++j) tmp[j] = f2bf(gcn_w[(kb * 8 + j) * 128 + d]);
    uint4 o;
    o.x = (u32)tmp[0] | ((u32)tmp[1] << 16);
    o.y = (u32)tmp[2] | ((u32)tmp[3] << 16);
    o.z = (u32)tmp[4] | ((u32)tmp[5] << 16);
    o.w = (u32)tmp[6] | ((u32)tmp[7] << 16);
    *(uint4*)&Wsw[(size_t)s * 8] = o;
  } else {
    const int tile = bid - 9;  // [nt 32][kt 32]
    const int n0 = (tile >> 5) * 64, m0 = (tile & 31) * 64;
#pragma unroll
    for (int k = 0; k < 4; ++k) {
      const int s = t + k * 256;  // 1024 float4 slots
      const int row = s >> 4, c4 = (s & 15) * 4;
      const float4 f = *(const float4*)&adj[(size_t)(n0 + row) * 2048 + m0 + c4];
      uint2 pk;
      pk.x = (u32)f2bf(f.x) | ((u32)f2bf(f.y) << 16);
      pk.y = (u32)f2bf(f.z) | ((u32)f2bf(f.w) << 16);
      *(uint2*)&ts[row * 136 + c4] = pk;
    }
    __syncthreads();
#pragma unroll
    for (int k = 0; k < 2; ++k) {
      const int s = t + k * 256;  // [kb 8][row 64]
      const int kb = s >> 6, row = s & 63;
      const uint4 v = *(const uint4*)&ts[row * 136 + kb * 8];
      *(uint4*)&adj_sw[(size_t)tile * 4096 + (size_t)s * 8] = v;
    }
  }
}

// ---------------- K_support: reads x fp32 directly, casts in-kernel ----------
__global__ __launch_bounds__(256) void k_support(const float* __restrict__ x,
                                                 const u16* __restrict__ Wsw,
                                                 u16* __restrict__ suppT_sw) {
  const int m0g = blockIdx.x * 128;
  const int t = threadIdx.x, w = t >> 6, l = t & 63;
  const int lg = l >> 4, lr = l & 15;
  __shared__ __align__(16) u16 ts[128 * 136];  // 34.8KB x bf16 tile; reused as os
  __shared__ __align__(16) u16 Bs[16384];      // 32KB W image
#pragma unroll
  for (int i = 0; i < 8; ++i) {
    const int s0 = i * 256 + w * 64;
    gload16(Wsw + (size_t)(s0 + l) * 8, &Bs[(size_t)s0 * 8]);
  }
#pragma unroll
  for (int k = 0; k < 16; ++k) {
    const int s = t + k * 256;  // [row 128][c4 32]
    const int row = s >> 5, c4 = (s & 31) * 4;
    const float4 f = *(const float4*)&x[(size_t)(m0g + row) * 128 + c4];
    uint2 pk;
    pk.x = (u32)f2bf(f.x) | ((u32)f2bf(f.y) << 16);
    pk.y = (u32)f2bf(f.z) | ((u32)f2bf(f.w) << 16);
    *(uint2*)&ts[row * 136 + c4] = pk;
  }
  __syncthreads();
  f32x4 acc[2][8];
#pragma unroll
  for (int mf = 0; mf < 2; ++mf)
#pragma unroll
    for (int nf = 0; nf < 8; ++nf) {
      acc[mf][nf][0] = 0.f; acc[mf][nf][1] = 0.f;
      acc[mf][nf][2] = 0.f; acc[mf][nf][3] = 0.f;
    }
#pragma unroll
  for (int ks = 0; ks < 4; ++ks) {
    const int kb = ks * 4 + lg;
    const bf16x8 a0 = *(const bf16x8*)&ts[(w * 32 + lr) * 136 + kb * 8];
    const bf16x8 a1 = *(const bf16x8*)&ts[(w * 32 + 16 + lr) * 136 + kb * 8];
#pragma unroll
    for (int nf = 0; nf < 8; ++nf) {
      const bf16x8 b = *(const bf16x8*)&Bs[((size_t)kb * 128 + nf * 16 + lr) * 8];
      acc[0][nf] = mfma16(a0, b, acc[0][nf]);
      acc[1][nf] = mfma16(a1, b, acc[1][nf]);
    }
  }
  __syncthreads();
  u16* os = ts;  // transpose: os[d][m_local], stride 136 u16
#pragma unroll
  for (int nf = 0; nf < 8; ++nf) {
    const int d = nf * 16 + lr;
#pragma unroll
    for (int mf = 0; mf < 2; ++mf) {
      const int mb = w * 32 + mf * 16 + lg * 4;
      const u32 p0 = (u32)f2bf(acc[mf][nf][0]) | ((u32)f2bf(acc[mf][nf][1]) << 16);
      const u32 p1 = (u32)f2bf(acc[mf][nf][2]) | ((u32)f2bf(acc[mf][nf][3]) << 16);
      *(u32*)&os[d * 136 + mb] = p0;
      *(u32*)&os[d * 136 + mb + 2] = p1;
    }
  }
  __syncthreads();
  const int b = m0g >> 11, mt0 = (m0g & 2047) >> 6;
#pragma unroll
  for (int i = 0; i < 8; ++i) {
    const int s = i * 256 + t;  // [kt 2][kb 8][d 128]
    const int kt = s >> 10, kb = (s >> 7) & 7, d = s & 127;
    const uint4 v = *(const uint4*)&os[d * 136 + kt * 64 + kb * 8];
    *(uint4*)&suppT_sw[((size_t)((b * 32 + mt0 + kt) * 8 + kb)) * 1024 + (size_t)d * 8] = v;
  }
}

// ---------------- K_gcn: 64x128 tile, BK=64, 8 waves, XCD-swizzled -----------
__global__ __launch_bounds__(512) void k_gcn(const u16* __restrict__ adj_sw,
                                             const u16* __restrict__ suppT_sw,
                                             const float* __restrict__ bias,
                                             float* __restrict__ h,
                                             float* __restrict__ psum,
                                             float* __restrict__ psq) {
  // XCD swizzle: each XCD owns 2 consecutive b's -> suppT panel L2-resident
  const int flat = blockIdx.y * 32 + blockIdx.x;  // 0..511
  const int nf2 = (flat & 7) * 64 + (flat >> 3);
  const int b = nf2 >> 5, nt = nf2 & 31;
  const int n0 = nt * 64;
  const int t = threadIdx.x;
  const int w = t >> 6, l = t & 63;
  const int wm = w >> 1, wn = w & 1;
  const int lg = l >> 4, lr = l & 15;
  __shared__ __align__(16) u16 As[2][4096];
  __shared__ __align__(16) u16 Bs[2][8192];
  __shared__ float redS[4][128], redQ[4][128];

  f32x4 acc[4];
#pragma unroll
  for (int nf = 0; nf < 4; ++nf) {
    acc[nf][0] = 0.f; acc[nf][1] = 0.f;
    acc[nf][2] = 0.f; acc[nf][3] = 0.f;
  }

#define GCN_STAGE(buf, kt)                                                        \
  {                                                                               \
    gload16(adj_sw + ((size_t)(nt * 32 + (kt))) * 4096 + (size_t)t * 8,           \
            &As[buf][t * 8]);                                                     \
    _Pragma("unroll") for (int i = 0; i < 2; ++i) {                               \
      const int s = i * 512 + t;                                                  \
      gload16(suppT_sw + ((size_t)(b * 32 + (kt))) * 8192 + (size_t)s * 8,        \
              &Bs[buf][s * 8]);                                                   \
    }                                                                             \
  }

  GCN_STAGE(0, 0);
  __syncthreads();
  for (int kt = 0; kt < 32; ++kt) {
    const int cur = kt & 1;
    if (kt + 1 < 32) GCN_STAGE(cur ^ 1, kt + 1);
#pragma unroll
    for (int kb = 0; kb < 2; ++kb) {
      const int ko = kb * 4 + lg;
      const bf16x8 a0 = *(const bf16x8*)&As[cur][(ko * 64 + wm * 16 + lr) * 8];
      const bf16x8 b0 = *(const bf16x8*)&Bs[cur][(ko * 128 + wn * 64 + lr) * 8];
      const bf16x8 b1 = *(const bf16x8*)&Bs[cur][(ko * 128 + wn * 64 + 16 + lr) * 8];
      const bf16x8 b2 = *(const bf16x8*)&Bs[cur][(ko * 128 + wn * 64 + 32 + lr) * 8];
      const bf16x8 b3 = *(const bf16x8*)&Bs[cur][(ko * 128 + wn * 64 + 48 + lr) * 8];
      acc[0] = mfma16(a0, b0, acc[0]);
      acc[1] = mfma16(a0, b1, acc[1]);
      acc[2] = mfma16(a0, b2, acc[2]);
      acc[3] = mfma16(a0, b3, acc[3]);
    }
    __syncthreads();
  }
#undef GCN_STAGE
#pragma unroll
  for (int nf = 0; nf < 4; ++nf) {
    const int d = wn * 64 + nf * 16 + lr;
    const float bv = bias[d];
    float s = 0.f, q = 0.f;
#pragma unroll
    for (int r = 0; r < 4; ++r) {
      const float v = acc[nf][r] + bv;
      const int row = n0 + wm * 16 + lg * 4 + r;
      h[((size_t)(b * NN + row)) * NH + d] = v;
      s += v;
      q = fmaf(v, v, q);
    }
    s += __shfl_xor(s, 16);
    s += __shfl_xor(s, 32);
    q += __shfl_xor(q, 16);
    q += __shfl_xor(q, 32);
    if (lg == 0) {
      redS[wm][d] = s;
      redQ[wm][d] = q;
    }
  }
  __syncthreads();
  if (t < 128) {
    const int blk = b * 32 + nt;
    psum[blk * 128 + t] = redS[0][t] + redS[1][t] + redS[2][t] + redS[3][t];
    psq[blk * 128 + t] = redQ[0][t] + redQ[1][t] + redQ[2][t] + redQ[3][t];
  }
}

// ---------------- BN finalize ------------------------------------------------
__global__ __launch_bounds__(1024) void k_bnstat2(const float* __restrict__ psum,
                                                  const float* __restrict__ psq,
                                                  const float* __restrict__ gamma,
                                                  const float* __restrict__ beta,
                                                  float* __restrict__ scale,
                                                  float* __restrict__ shift) {
  const int t = threadIdx.x;
  const int d = t & 127;
  const int g = t >> 7;
  float s = 0.f, q = 0.f;
  for (int i = g; i < 512; i += 8) {
    s += psum[i * 128 + d];
    q += psq[i * 128 + d];
  }
  __shared__ float ls[8][128], lq[8][128];
  ls[g][d] = s;
  lq[g][d] = q;
  __syncthreads();
  if (t < 128) {
    s = 0.f;
    q = 0.f;
#pragma unroll
    for (int i = 0; i < 8; ++i) {
      s += ls[i][t];
      q += lq[i][t];
    }
    const float inv = 1.f / (float)(NB * NN);
    const float mean = s * inv;
    const float var = q * inv - mean * mean;
    const float sc = gamma[t] * rsqrtf(var + 1e-5f);
    scale[t] = sc;
    shift[t] = beta[t] - mean * sc;
  }
}

// ---------------- K_hp: MFMA version -----------------------------------------
__global__ __launch_bounds__(256) void k_hp(const float* __restrict__ h,
                                            const float* __restrict__ scale,
                                            const float* __restrict__ shift,
                                            const u16* __restrict__ Wg_sw,
                                            u16* __restrict__ hp_sw) {
  const int row0 = blockIdx.x * 64;
  const int t = threadIdx.x, w = t >> 6, l = t & 63;
  const int lg = l >> 4, lr = l & 15;
  __shared__ __align__(16) u16 him[8192];
  __shared__ __align__(16) u16 Wg[8192];
  __shared__ __align__(16) u16 hos[64][72];
  __shared__ float scs[128], shs[128];
#pragma unroll
  for (int i = 0; i < 4; ++i) {
    const int s0 = i * 256 + w * 64;
    gload16(Wg_sw + (size_t)(s0 + l) * 8, &Wg[(size_t)s0 * 8]);
  }
  if (t < 128) {
    scs[t] = scale[t];
    shs[t] = shift[t];
  }
  __syncthreads();
#pragma unroll
  for (int k = 0; k < 4; ++k) {
    const int s = t + k * 256;  // [row 64][kb 16]
    const int row = s >> 4, kb = s & 15;
    const float4 v0 = *(const float4*)&h[(size_t)(row0 + row) * NH + kb * 8];
    const float4 v1 = *(const float4*)&h[(size_t)(row0 + row) * NH + kb * 8 + 4];
    u16 p[8];
    p[0] = f2bf(fmaxf(fmaf(v0.x, scs[kb * 8 + 0], shs[kb * 8 + 0]), 0.f));
    p[1] = f2bf(fmaxf(fmaf(v0.y, scs[kb * 8 + 1], shs[kb * 8 + 1]), 0.f));
    p[2] = f2bf(fmaxf(fmaf(v0.z, scs[kb * 8 + 2], shs[kb * 8 + 2]), 0.f));
    p[3] = f2bf(fmaxf(fmaf(v0.w, scs[kb * 8 + 3], shs[kb * 8 + 3]), 0.f));
    p[4] = f2bf(fmaxf(fmaf(v1.x, scs[kb * 8 + 4], shs[kb * 8 + 4]), 0.f));
    p[5] = f2bf(fmaxf(fmaf(v1.y, scs[kb * 8 + 5], shs[kb * 8 + 5]), 0.f));
    p[6] = f2bf(fmaxf(fmaf(v1.z, scs[kb * 8 + 6], shs[kb * 8 + 6]), 0.f));
    p[7] = f2bf(fmaxf(fmaf(v1.w, scs[kb * 8 + 7], shs[kb * 8 + 7]), 0.f));
    uint4 o;
    o.x = (u32)p[0] | ((u32)p[1] << 16);
    o.y = (u32)p[2] | ((u32)p[3] << 16);
    o.z = (u32)p[4] | ((u32)p[5] << 16);
    o.w = (u32)p[6] | ((u32)p[7] << 16);
    const int boff = (row * 256 + kb * 16) ^ ((row & 7) << 4);
    *(uint4*)&him[boff >> 1] = o;
  }
  __syncthreads();
  f32x4 acc[4];
#pragma unroll
  for (int nf = 0; nf < 4; ++nf) {
    acc[nf][0] = 0.f; acc[nf][1] = 0.f;
    acc[nf][2] = 0.f; acc[nf][3] = 0.f;
  }
#pragma unroll
  for (int kks = 0; kks < 4; ++kks) {
    const int ko = kks * 4 + lg;
    const int arow = w * 16 + lr;
    const int aoff = (arow * 256 + ko * 16) ^ ((arow & 7) << 4);
    const bf16x8 a = *(const bf16x8*)&him[aoff >> 1];
#pragma unroll
    for (int nf = 0; nf < 4; ++nf) {
      const bf16x8 bfr = *(const bf16x8*)&Wg[(ko * 64 + nf * 16 + lr) * 8];
      acc[nf] = mfma16(a, bfr, acc[nf]);
    }
  }
#pragma unroll
  for (int nf = 0; nf < 4; ++nf) {
    const int col = nf * 16 + lr;
#pragma unroll
    for (int r = 0; r < 4; ++r) {
      hos[w * 16 + lg * 4 + r][col] = f2bf(acc[nf][r]);
    }
  }
  __syncthreads();
  const size_t tbase = (size_t)blockIdx.x * 4096;
#pragma unroll
  for (int k = 0; k < 2; ++k) {
    const int s = t + k * 256;
    const int kb = s >> 6, r6 = s & 63;
    const uint2 lo = *(const uint2*)&hos[r6][kb * 8];
    const uint2 hi = *(const uint2*)&hos[r6][kb * 8 + 4];
    uint4 o;
    o.x = lo.x; o.y = lo.y; o.z = hi.x; o.w = hi.y;
    *(uint4*)&hp_sw[tbase + kb * 512 + r6 * 8] = o;
  }
}

// ---------------- attn XCD swizzle helper ------------------------------------
__device__ __forceinline__ void attn_swz(int& b, int& nt, int& qtr) {
  const int flat = blockIdx.y * 512 + blockIdx.x;  // 0..2047
  const int lf = (flat & 7) * 256 + (flat >> 3);
  b = lf >> 7;
  const int rem = lf & 127;
  qtr = rem >> 5;
  nt = rem & 31;
}

// ---------------- K_attnA: partial D over m-quarter --------------------------
__global__ __launch_bounds__(256) void k_attnA(const u16* __restrict__ hp_sw,
                                               float* __restrict__ Dpart) {
  int b, nt, qtr;
  attn_swz(b, nt, qtr);
  const int t = threadIdx.x, w = t >> 6, l = t & 63;
  const int lg = l >> 4, lr = l & 15;
  __shared__ __align__(16) u16 Cs[2][4096];
  const u16* rbase = hp_sw + (size_t)(b * 32 + nt) * 4096;
  const int qrow = (w << 4) + lr;
  const bf16x8 bq0 = *(const bf16x8*)&rbase[(lg * 64 + qrow) * 8];
  const bf16x8 bq1 = *(const bf16x8*)&rbase[((lg + 4) * 64 + qrow) * 8];
  const u16* cb = hp_sw + (size_t)(b * 32 + qtr * 8) * 4096;
#pragma unroll
  for (int i = 0; i < 2; ++i) gload16(cb + (size_t)(i * 256 + t) * 8, &Cs[0][(i * 256 + t) * 8]);
  __syncthreads();
  float S = 0.f;
  for (int mt = 0; mt < 8; ++mt) {
    const int cur = mt & 1;
    if (mt + 1 < 8) {
#pragma unroll
      for (int i = 0; i < 2; ++i)
        gload16(cb + (size_t)(mt + 1) * 4096 + (size_t)(i * 256 + t) * 8,
                &Cs[cur ^ 1][(i * 256 + t) * 8]);
    }
#pragma unroll
    for (int mf = 0; mf < 4; ++mf) {
      const bf16x8 a0 = *(const bf16x8*)&Cs[cur][(lg * 64 + mf * 16 + lr) * 8];
      const bf16x8 a1 = *(const bf16x8*)&Cs[cur][((lg + 4) * 64 + mf * 16 + lr) * 8];
      f32x4 z;
      z[0] = 0.f; z[1] = 0.f; z[2] = 0.f; z[3] = 0.f;
      z = mfma16(a0, bq0, z);
      z = mfma16(a1, bq1, z);
      S += explr(z[0]) + explr(z[1]) + explr(z[2]) + explr(z[3]);
    }
    __syncthreads();
  }
  S += __shfl_xor(S, 16);
  S += __shfl_xor(S, 32);
  if (l < 16) Dpart[qtr * 32768 + b * NN + nt * 64 + qrow] = S;
}

// ---------------- K_attnB: partial S (computes iD in-block) ------------------
__global__ __launch_bounds__(256) void k_attnB(const u16* __restrict__ hp_sw,
                                               const float* __restrict__ Dpart,
                                               float* __restrict__ Spart) {
  int b, nt, qtr;
  attn_swz(b, nt, qtr);
  const int t = threadIdx.x, w = t >> 6, l = t & 63;
  const int lg = l >> 4, lr = l & 15;
  __shared__ __align__(16) u16 Cs[2][4096];
  __shared__ float iDs[512];
  const u16* rbase = hp_sw + (size_t)(b * 32 + nt) * 4096;
  const int qrow = (w << 4) + lr;
  const bf16x8 bq0 = *(const bf16x8*)&rbase[(lg * 64 + qrow) * 8];
  const bf16x8 bq1 = *(const bf16x8*)&rbase[((lg + 4) * 64 + qrow) * 8];
  const u16* cb = hp_sw + (size_t)(b * 32 + qtr * 8) * 4096;
#pragma unroll
  for (int i = 0; i < 2; ++i) gload16(cb + (size_t)(i * 256 + t) * 8, &Cs[0][(i * 256 + t) * 8]);
#pragma unroll
  for (int i = 0; i < 2; ++i) {
    const int idx = t + i * 256;
    const int n = b * NN + qtr * 512 + idx;
    iDs[idx] = 1.f / (Dpart[n] + Dpart[32768 + n] + Dpart[65536 + n] + Dpart[98304 + n]);
  }
  __syncthreads();
  float S = 0.f;
  for (int mt = 0; mt < 8; ++mt) {
    const int cur = mt & 1;
    if (mt + 1 < 8) {
#pragma unroll
      for (int i = 0; i < 2; ++i)
        gload16(cb + (size_t)(mt + 1) * 4096 + (size_t)(i * 256 + t) * 8,
                &Cs[cur ^ 1][(i * 256 + t) * 8]);
    }
#pragma unroll
    for (int mf = 0; mf < 4; ++mf) {
      const bf16x8 a0 = *(const bf16x8*)&Cs[cur][(lg * 64 + mf * 16 + lr) * 8];
      const bf16x8 a1 = *(const bf16x8*)&Cs[cur][((lg + 4) * 64 + mf * 16 + lr) * 8];
      f32x4 z;
      z[0] = 0.f; z[1] = 0.f; z[2] = 0.f; z[3] = 0.f;
      z = mfma16(a0, bq0, z);
      z = mfma16(a1, bq1, z);
      const float4 dv = *(const float4*)&iDs[mt * 64 + mf * 16 + lg * 4];
      S = fmaf(explr(z[0]), dv.x, S);
      S = fmaf(explr(z[1]), dv.y, S);
      S = fmaf(explr(z[2]), dv.z, S);
      S = fmaf(explr(z[3]), dv.w, S);
    }
    __syncthreads();
  }
  S += __shfl_xor(S, 16);
  S += __shfl_xor(S, 32);
  if (l < 16) Spart[qtr * 32768 + b * NN + nt * 64 + qrow] = S;
}

// ---------------- K_scale: out = hp * (S0+S1+S2+S3) --------------------------
__global__ __launch_bounds__(256) void k_scale(const u16* __restrict__ hp_sw,
                                               const float* __restrict__ Spart,
                                               float* __restrict__ out) {
  const int bx = blockIdx.x;
  const int b = bx >> 5, nt = bx & 31;
  const int t = threadIdx.x;
  __shared__ float Sv[64];
  if (t < 64) {
    const int n = b * NN + nt * 64 + t;
    Sv[t] = Spart[n] + Spart[32768 + n] + Spart[65536 + n] + Spart[98304 + n];
  }
  __syncthreads();
  const u16* rbase = hp_sw + (size_t)(b * 32 + nt) * 4096;
  const int row = t >> 2;
  const float sc = Sv[row];
  const size_t R = (size_t)b * NN + nt * 64 + row;
#pragma unroll
  for (int hh = 0; hh < 2; ++hh) {
    const int kb = (t & 3) * 2 + hh;
    const u16* src = &rbase[(kb * 64 + row) * 8];
    float4 o0, o1;
    o0.x = bf2f(src[0]) * sc;
    o0.y = bf2f(src[1]) * sc;
    o0.z = bf2f(src[2]) * sc;
    o0.w = bf2f(src[3]) * sc;
    o1.x = bf2f(src[4]) * sc;
    o1.y = bf2f(src[5]) * sc;
    o1.z = bf2f(src[6]) * sc;
    o1.w = bf2f(src[7]) * sc;
    *(float4*)&out[R * NO + kb * 8] = o0;
    *(float4*)&out[R * NO + kb * 8 + 4] = o1;
  }
}

extern "C" void kernel_launch(void* const* d_in, const int* in_sizes, int n_in,
                              void* d_out, int out_size, void* d_ws, size_t ws_size,
                              hipStream_t stream) {
  const float* x = (const float*)d_in[0];
  // d_in[1] = adj (unused)
  const float* adj_gcn = (const float*)d_in[2];
  const float* gcn_w = (const float*)d_in[3];
  const float* gcn_b = (const float*)d_in[4];
  const float* gamma = (const float*)d_in[5];
  const float* beta = (const float*)d_in[6];
  const float* gat_w = (const float*)d_in[7];
  float* out = (float*)d_out;
  float* ws = (float*)d_ws;

  // workspace layout (float units):
  u16* adj_sw = (u16*)ws;                  // [0, 2M)
  u16* suppT_sw = (u16*)(ws + 2097152);    // [2M, 4M)
  float* hbuf = ws + 4194304;              // [4M, 8M)
  u16* hp_sw = (u16*)(ws + 8388608);       // [8M, 9M)
  float* psum = ws + 9437184;              // 65536
  float* psq = psum + 65536;               // 65536
  float* scale = psq + 65536;              // 128
  float* shift = scale + 128;              // 128
  u16* Wg_sw = (u16*)(shift + 128);        // 8192 u16 (4096 f)
  u16* Wsw = (u16*)(shift + 128 + 4096);   // 16384 u16 (8192 f)
  float* Dpart = ws + 9617664;             // 131072
  float* Spart = Dpart + 131072;           // 131072

  k_prep<<<dim3(1033), dim3(256), 0, stream>>>(adj_gcn, gcn_w, gat_w, adj_sw, Wg_sw, Wsw);
  k_support<<<dim3(256), dim3(256), 0, stream>>>(x, Wsw, suppT_sw);
  k_gcn<<<dim3(32, 16), dim3(512), 0, stream>>>(adj_sw, suppT_sw, gcn_b, hbuf, psum, psq);
  k_bnstat2<<<dim3(1), dim3(1024), 0, stream>>>(psum, psq, gamma, beta, scale, shift);
  k_hp<<<dim3(512), dim3(256), 0, stream>>>(hbuf, scale, shift, Wg_sw, hp_sw);
  k_attnA<<<dim3(512, 4), dim3(256), 0, stream>>>(hp_sw, Dpart);
  k_attnB<<<dim3(512, 4), dim3(256), 0, stream>>>(hp_sw, Dpart, Spart);
  k_scale<<<dim3(512), dim3(256), 0, stream>>>(hp_sw, Spart, out);
}